// Round 3
// baseline (873.920 us; speedup 1.0000x reference)
//
#include <hip/hip_runtime.h>
#include <hip/hip_bf16.h>
#include <cstdint>
#include <cstddef>

#define T_TOK 1024
#define H_DIM 2048
#define NH 32
#define HS 64
#define TH (T_TOK * H_DIM)
#define HH (H_DIM * H_DIM)

using short8 = __attribute__((ext_vector_type(8))) short;
using f32x4  = __attribute__((ext_vector_type(4))) float;
typedef __hip_bfloat16 bf16;

__device__ __forceinline__ float sigmoidf_(float x) { return 1.0f / (1.0f + expf(-x)); }

__device__ __forceinline__ float wsum64(float v) {
#pragma unroll
    for (int m = 32; m; m >>= 1) v += __shfl_xor(v, m, 64);
    return v;
}

// ---------------- cast big weights fp32 -> bf16 ----------------
struct CastPar { const float* src[4]; bf16* dst[4]; };
__global__ __launch_bounds__(256) void castw_kernel(CastPar p) {
    int z = blockIdx.z;
    const float4* s = (const float4*)p.src[z];
    bf16* d = p.dst[z];
    int i = blockIdx.x * 256 + threadIdx.x;
    float4 v = s[i];
    int b = i * 4;
    d[b + 0] = __float2bfloat16(v.x);
    d[b + 1] = __float2bfloat16(v.y);
    d[b + 2] = __float2bfloat16(v.z);
    d[b + 3] = __float2bfloat16(v.w);
}

// ---------------- transpose + cast small weights ----------------
struct TPar { const float* src[8]; bf16* dst[8]; int R[8]; int C[8]; };
__global__ __launch_bounds__(256) void transpose_kernel(TPar p) {
    int z = blockIdx.z;
    int R = p.R[z], C = p.C[z];
    int e = blockIdx.x * 256 + threadIdx.x;
    if (e >= R * C) return;
    int r = e / C, c = e % C;
    p.dst[z][(size_t)c * R + r] = __float2bfloat16(p.src[z][e]);
}

// ---------------- LayerNorm (ln1) ----------------
__global__ __launch_bounds__(256) void ln_kernel(const float* __restrict__ x,
                                                 const float* __restrict__ w,
                                                 const float* __restrict__ b,
                                                 float* __restrict__ xn,
                                                 float* __restrict__ s1out) {
    int t = blockIdx.x, tid = threadIdx.x;
    const float* xt = x + (size_t)t * H_DIM;
    float v[8]; float s = 0.f, s2 = 0.f;
#pragma unroll
    for (int e = 0; e < 8; e++) { v[e] = xt[tid + 256 * e]; s += v[e]; s2 += v[e] * v[e]; }
    s = wsum64(s); s2 = wsum64(s2);
    __shared__ float ls[8];
    int wid = tid >> 6, ln = tid & 63;
    if (ln == 0) { ls[wid] = s; ls[4 + wid] = s2; }
    __syncthreads();
    s = ls[0] + ls[1] + ls[2] + ls[3];
    s2 = ls[4] + ls[5] + ls[6] + ls[7];
    float mu = s * (1.f / H_DIM);
    float var = s2 * (1.f / H_DIM) - mu * mu;
    float inv = rsqrtf(var + 1e-5f);
#pragma unroll
    for (int e = 0; e < 8; e++) {
        int h = tid + 256 * e;
        float o = (v[e] - mu) * inv * w[h] + b[h];
        xn[(size_t)t * H_DIM + h] = o;
        if (t == T_TOK - 1) s1out[h] = o;
    }
}

// ---------------- token-shift mixes ----------------
struct MixPar { const float* xn; const float* state1; const float* mv[6]; bf16* out[6]; };
__global__ __launch_bounds__(256) void mix_kernel(MixPar p) {
    int t = blockIdx.x, tid = threadIdx.x;
#pragma unroll
    for (int e = 0; e < 8; e++) {
        int h = tid + 256 * e;
        size_t idx = (size_t)t * H_DIM + h;
        float cur = p.xn[idx];
        float prev = (t == 0) ? p.state1[h] : p.xn[idx - H_DIM];
        float sx = prev - cur;
#pragma unroll
        for (int q = 0; q < 6; q++)
            p.out[q][idx] = __float2bfloat16(cur + p.mv[q][h] * sx);
    }
}

// ======== big GEMM (M=1024, N=2048, K=2048): global_load_lds staging ========
typedef const __attribute__((address_space(1))) uint32_t* gp1_t;
typedef __attribute__((address_space(3))) uint32_t* lp3_t;
__device__ __forceinline__ void async16(const bf16* g, short* l) {
    __builtin_amdgcn_global_load_lds((gp1_t)g, (lp3_t)l, 16, 0, 0);
}

struct BGPar { const bf16* X[4]; const bf16* W[4]; float* out[4]; const float* resid[4]; };
__global__ __launch_bounds__(256) void bgemm_kernel(BGPar p) {
    int z = blockIdx.z;
    const bf16* __restrict__ X = p.X[z];
    const bf16* __restrict__ W = p.W[z];
    float* __restrict__ out = p.out[z];
    const float* __restrict__ resid = p.resid[z];

    __shared__ short As[128 * 32];   // [row][32k], 64 B/row, unpadded (global_load_lds layout)
    __shared__ short Bs[128 * 32];

    int m0 = blockIdx.y * 128, n0 = blockIdx.x * 128;
    int tid = threadIdx.x, lane = tid & 63, wv = tid >> 6;
    int m_off = (wv >> 1) * 64, n_off = (wv & 1) * 64;
    int lr = lane & 15, lq = lane >> 4;

    // staging: wave wv owns rows [wv*32, wv*32+32) of each tile, 2 issues of 16 rows.
    // lane l -> row +(l>>2), col 8*(l&3); LDS dest = chunk base + l*16 bytes (matches row*64+col*2).
    int srow = lane >> 2;
    int scol = (lane & 3) * 8;
    const bf16* Ag0 = X + (size_t)(m0 + wv * 32 + srow) * 2048 + scol;
    const bf16* Ag1 = Ag0 + (size_t)16 * 2048;
    const bf16* Bg0 = W + (size_t)(n0 + wv * 32 + srow) * 2048 + scol;
    const bf16* Bg1 = Bg0 + (size_t)16 * 2048;
    short* Al0 = &As[(wv * 32) * 32];
    short* Al1 = &As[(wv * 32 + 16) * 32];
    short* Bl0 = &Bs[(wv * 32) * 32];
    short* Bl1 = &Bs[(wv * 32 + 16) * 32];

    f32x4 acc[4][4];
#pragma unroll
    for (int a = 0; a < 4; a++)
#pragma unroll
        for (int b = 0; b < 4; b++)
#pragma unroll
            for (int r = 0; r < 4; r++) acc[a][b][r] = 0.f;

    for (int k0 = 0; k0 < 2048; k0 += 32) {
        async16(Ag0 + k0, Al0);
        async16(Ag1 + k0, Al1);
        async16(Bg0 + k0, Bl0);
        async16(Bg1 + k0, Bl1);
        __syncthreads();           // compiler inserts vmcnt(0) drain before barrier
        short8 af[4], bfr[4];
#pragma unroll
        for (int mi = 0; mi < 4; mi++)
            af[mi] = *(const short8*)&As[(m_off + mi * 16 + lr) * 32 + lq * 8];
#pragma unroll
        for (int ni = 0; ni < 4; ni++)
            bfr[ni] = *(const short8*)&Bs[(n_off + ni * 16 + lr) * 32 + lq * 8];
#pragma unroll
        for (int mi = 0; mi < 4; mi++)
#pragma unroll
            for (int ni = 0; ni < 4; ni++)
                acc[mi][ni] = __builtin_amdgcn_mfma_f32_16x16x32_bf16(af[mi], bfr[ni], acc[mi][ni], 0, 0, 0);
        __syncthreads();
    }
#pragma unroll
    for (int mi = 0; mi < 4; mi++)
#pragma unroll
        for (int ni = 0; ni < 4; ni++)
#pragma unroll
            for (int r = 0; r < 4; r++) {
                int rowg = m0 + m_off + mi * 16 + lq * 4 + r;
                int colg = n0 + n_off + ni * 16 + lr;
                size_t o = (size_t)rowg * 2048 + colg;
                float v = acc[mi][ni][r];
                if (resid) v += resid[o];
                out[o] = v;
            }
}

// ---------------- generic small-GEMM (vector-load staging, guarded N) ----------------
#define BM 128
#define BN 128
#define BK 32
#define LDK 40

__device__ __forceinline__ void gemm_core(const bf16* __restrict__ X, const bf16* __restrict__ W,
                                          int M, int N, int K, int act,
                                          const float* __restrict__ bias,
                                          float* __restrict__ outF, bf16* __restrict__ outB) {
    __shared__ short As[BM * LDK];
    __shared__ short Bs[BN * LDK];
    int m0 = blockIdx.y * BM, n0 = blockIdx.x * BN;
    if (n0 >= N) return;
    int tid = threadIdx.x;
    int lane = tid & 63, wid = tid >> 6;
    int m_off = (wid >> 1) * 64, n_off = (wid & 1) * 64;
    int lr = lane & 15, lq = lane >> 4;

    f32x4 acc[4][4];
#pragma unroll
    for (int a = 0; a < 4; a++)
#pragma unroll
        for (int b = 0; b < 4; b++)
#pragma unroll
            for (int r = 0; r < 4; r++) acc[a][b][r] = 0.f;

    for (int k0 = 0; k0 < K; k0 += BK) {
#pragma unroll
        for (int it = 0; it < 2; it++) {
            int c = tid + it * 256;
            int r = c >> 2;
            int cc = (c & 3) * 8;
            uint4 va = *(const uint4*)(X + (size_t)(m0 + r) * K + k0 + cc);
            *(uint4*)&As[r * LDK + cc] = va;
            uint4 vb;
            if (n0 + r < N) vb = *(const uint4*)(W + (size_t)(n0 + r) * K + k0 + cc);
            else            vb = make_uint4(0u, 0u, 0u, 0u);
            *(uint4*)&Bs[r * LDK + cc] = vb;
        }
        __syncthreads();
        short8 af[4], bfr[4];
#pragma unroll
        for (int mi = 0; mi < 4; mi++)
            af[mi] = *(const short8*)&As[(m_off + mi * 16 + lr) * LDK + lq * 8];
#pragma unroll
        for (int ni = 0; ni < 4; ni++)
            bfr[ni] = *(const short8*)&Bs[(n_off + ni * 16 + lr) * LDK + lq * 8];
#pragma unroll
        for (int mi = 0; mi < 4; mi++)
#pragma unroll
            for (int ni = 0; ni < 4; ni++)
                acc[mi][ni] = __builtin_amdgcn_mfma_f32_16x16x32_bf16(af[mi], bfr[ni], acc[mi][ni], 0, 0, 0);
        __syncthreads();
    }
#pragma unroll
    for (int mi = 0; mi < 4; mi++)
#pragma unroll
        for (int ni = 0; ni < 4; ni++)
#pragma unroll
            for (int r = 0; r < 4; r++) {
                int rowg = m0 + m_off + mi * 16 + lq * 4 + r;
                int colg = n0 + n_off + ni * 16 + lr;
                if (colg < N) {
                    float v = acc[mi][ni][r];
                    if (bias) v += bias[colg];
                    if (act == 1) v = sigmoidf_(v);
                    else if (act == 2) v = tanhf(v);
                    size_t o = (size_t)rowg * N + colg;
                    if (outF) outF[o] = v;
                    else      outB[o] = __float2bfloat16(v);
                }
            }
}

struct GPar {
    const bf16* X[4]; const bf16* W[4];
    float* outF[4]; bf16* outB[4];
    const float* bias[4];
    int N[4]; int K[4]; int act[4]; int M;
};
__global__ __launch_bounds__(256) void gemm_z_kernel(GPar p) {
    int z = blockIdx.z;
    gemm_core(p.X[z], p.W[z], p.M, p.N[z], p.K[z], p.act[z], p.bias[z], p.outF[z], p.outB[z]);
}

// ---------------- elementwise prep for the scan ----------------
__global__ __launch_bounds__(64) void prep_kernel(float* __restrict__ k_io, float* __restrict__ v_io,
                                                  const float* __restrict__ v_first,
                                                  const float* __restrict__ vres,
                                                  float* __restrict__ w_io, float* __restrict__ a_io,
                                                  float* __restrict__ as_out,
                                                  const float* __restrict__ k_k,
                                                  const float* __restrict__ k_a,
                                                  const float* __restrict__ w0) {
    int h = blockIdx.x, t = blockIdx.y, i = threadIdx.x;
    int hi = h * HS + i;
    size_t idx = (size_t)t * H_DIM + hi;
    float kf = k_io[idx];
    float kk = kf * k_k[hi];
    float ss = wsum64(kk * kk);
    float kkn = kk / (sqrtf(ss) + 1e-12f);
    float a = a_io[idx];
    k_io[idx] = kf * (1.f + (a - 1.f) * k_a[hi]);
    float vv = v_io[idx];
    v_io[idx] = vv + (v_first[idx] - vv) * vres[idx];
    w_io[idx] = expf(-0.606531f * sigmoidf_(w0[hi] + w_io[idx]));
    a_io[idx] = kkn * a;     // b_seq
    as_out[idx] = -kkn;      // a_seq
}

// ---------------- WKV7 scan: 2 ILP chains per wave ----------------
// Wave (h, q) owns row-groups gA=q (rows q*4..q*4+3) and gB=q+8 (rows +32).
// lane = il*16+jb: il = row-in-group (0..3), jb = 4-col block (0..15).
// Shared per-step vectors loaded ONCE (float4, 5 regs x4) for both chains;
// two independent fma/shfl chains interleave to hide ds_bpermute latency.
struct StepV { f32x4 w, a, b, k, r; float vA, vB; };

__device__ __forceinline__ StepV ldstep(const float* __restrict__ w_s,
                                        const float* __restrict__ as_s,
                                        const float* __restrict__ b_s,
                                        const float* __restrict__ k_s,
                                        const float* __restrict__ v_s,
                                        const float* __restrict__ r_s,
                                        int t, int hb, int jo, int rA, int rB) {
    size_t tb = (size_t)t * H_DIM + hb;
    StepV s;
    s.w = *(const f32x4*)(w_s + tb + jo);
    s.a = *(const f32x4*)(as_s + tb + jo);
    s.b = *(const f32x4*)(b_s + tb + jo);
    s.k = *(const f32x4*)(k_s + tb + jo);
    s.r = *(const f32x4*)(r_s + tb + jo);
    s.vA = v_s[tb + rA];
    s.vB = v_s[tb + rB];
    return s;
}

__device__ __forceinline__ float red16(float x) {
    x += __shfl_xor(x, 1, 64);
    x += __shfl_xor(x, 2, 64);
    x += __shfl_xor(x, 4, 64);
    x += __shfl_xor(x, 8, 64);
    return x;
}

__device__ __forceinline__ void step_compute(float SA[4], float SB[4], const StepV& s,
                                             float* __restrict__ y,
                                             int t, int hb, int rA, int rB, int jb) {
    float saA = 0.f, saB = 0.f;
#pragma unroll
    for (int e = 0; e < 4; e++) {
        SA[e] *= s.w[e]; saA = fmaf(SA[e], s.a[e], saA);
        SB[e] *= s.w[e]; saB = fmaf(SB[e], s.a[e], saB);
    }
    saA = red16(saA); saB = red16(saB);
    float oA = 0.f, oB = 0.f;
#pragma unroll
    for (int e = 0; e < 4; e++) {
        SA[e] = fmaf(saA, s.b[e], fmaf(s.vA, s.k[e], SA[e])); oA = fmaf(SA[e], s.r[e], oA);
        SB[e] = fmaf(saB, s.b[e], fmaf(s.vB, s.k[e], SB[e])); oB = fmaf(SB[e], s.r[e], oB);
    }
    oA = red16(oA); oB = red16(oB);
    if (jb == 0) {
        y[(size_t)t * H_DIM + hb + rA] = oA;
        y[(size_t)t * H_DIM + hb + rB] = oB;
    }
}

__global__ __launch_bounds__(64) void scan_kernel(const float* __restrict__ w_s,
                                                  const float* __restrict__ k_s,
                                                  const float* __restrict__ v_s,
                                                  const float* __restrict__ as_s,
                                                  const float* __restrict__ b_s,
                                                  const float* __restrict__ r_s,
                                                  const float* __restrict__ s2in,
                                                  float* __restrict__ y,
                                                  float* __restrict__ s2out) {
    int h = blockIdx.x, q = blockIdx.y;
    int lane = threadIdx.x;
    int il = lane >> 4, jb = lane & 15;
    int jo = jb * 4;
    int rA = q * 4 + il;
    int rB = rA + 32;
    int hb = h * HS;

    float SA[4], SB[4];
    {
        const float* sA = s2in + ((size_t)h * HS + rA) * HS + jo;
        const float* sB = s2in + ((size_t)h * HS + rB) * HS + jo;
        float4 a4 = *(const float4*)sA, b4 = *(const float4*)sB;
        SA[0] = a4.x; SA[1] = a4.y; SA[2] = a4.z; SA[3] = a4.w;
        SB[0] = b4.x; SB[1] = b4.y; SB[2] = b4.z; SB[3] = b4.w;
    }

#define LDS_(tt) ldstep(w_s, as_s, b_s, k_s, v_s, r_s, ((tt) < T_TOK ? (tt) : T_TOK - 1), hb, jo, rA, rB)
    StepV c0 = LDS_(0);
    StepV c1 = LDS_(1);
    for (int t = 0; t < T_TOK; t += 4) {
        StepV n0 = LDS_(t + 2); step_compute(SA, SB, c0, y, t,     hb, rA, rB, jb);
        StepV n1 = LDS_(t + 3); step_compute(SA, SB, c1, y, t + 1, hb, rA, rB, jb);
        c0 = LDS_(t + 4);       step_compute(SA, SB, n0, y, t + 2, hb, rA, rB, jb);
        c1 = LDS_(t + 5);       step_compute(SA, SB, n1, y, t + 3, hb, rA, rB, jb);
    }
#undef LDS_

    {
        float* dA = s2out + ((size_t)h * HS + rA) * HS + jo;
        float* dB = s2out + ((size_t)h * HS + rB) * HS + jo;
        float4 a4, b4;
        a4.x = SA[0]; a4.y = SA[1]; a4.z = SA[2]; a4.w = SA[3];
        b4.x = SB[0]; b4.y = SB[1]; b4.z = SB[2]; b4.w = SB[3];
        *(float4*)dA = a4; *(float4*)dB = b4;
    }
}

// ---------------- groupnorm + bonus + gate -> bf16 ----------------
__global__ __launch_bounds__(64) void post_kernel(const float* __restrict__ y,
                                                  const float* __restrict__ r_s,
                                                  const float* __restrict__ k_s,
                                                  const float* __restrict__ v_s,
                                                  const float* __restrict__ g_s,
                                                  const float* __restrict__ r_k,
                                                  const float* __restrict__ lnw,
                                                  const float* __restrict__ lnb,
                                                  bf16* __restrict__ ybig) {
    int h = blockIdx.x, t = blockIdx.y, i = threadIdx.x;
    int hi = h * HS + i;
    size_t idx = (size_t)t * H_DIM + hi;
    float yv = y[idx];
    float mu = wsum64(yv) * (1.f / HS);
    float d = yv - mu;
    float var = wsum64(d * d) * (1.f / HS);
    float yn = d * rsqrtf(var + 0.00064f);
    float bd = wsum64(r_s[idx] * k_s[idx] * r_k[hi]);
    float val = (yn * lnw[hi] + lnb[hi] + bd * v_s[idx]) * g_s[idx];
    ybig[idx] = __float2bfloat16(val);
}

// ---------------- launcher ----------------
extern "C" void kernel_launch(void* const* d_in, const int* in_sizes, int n_in,
                              void* d_out, int out_size, void* d_ws, size_t ws_size,
                              hipStream_t stream) {
    const float* x      = (const float*)d_in[0];
    const float* state1 = (const float*)d_in[1];
    const float* state2 = (const float*)d_in[2];
    const float* vfirst = (const float*)d_in[3];
    const float* x_r = (const float*)d_in[4];
    const float* x_w = (const float*)d_in[5];
    const float* x_k = (const float*)d_in[6];
    const float* x_v = (const float*)d_in[7];
    const float* x_a = (const float*)d_in[8];
    const float* x_g = (const float*)d_in[9];
    const float* W_r = (const float*)d_in[10];
    const float* W_k = (const float*)d_in[11];
    const float* W_v = (const float*)d_in[12];
    const float* W_o = (const float*)d_in[13];
    const float* w0 = (const float*)d_in[14];
    const float* w1 = (const float*)d_in[15];
    const float* w2 = (const float*)d_in[16];
    const float* a0 = (const float*)d_in[17];
    const float* a1 = (const float*)d_in[18];
    const float* a2 = (const float*)d_in[19];
    const float* v0 = (const float*)d_in[20];
    const float* v1 = (const float*)d_in[21];
    const float* v2 = (const float*)d_in[22];
    const float* g1 = (const float*)d_in[23];
    const float* g2 = (const float*)d_in[24];
    const float* k_k = (const float*)d_in[25];
    const float* k_a = (const float*)d_in[26];
    const float* r_k = (const float*)d_in[27];
    const float* ln_x_w = (const float*)d_in[28];
    const float* ln_x_b = (const float*)d_in[29];
    const float* ln1_w = (const float*)d_in[30];
    const float* ln1_b = (const float*)d_in[31];

    float* out0 = (float*)d_out;
    float* out1 = out0 + TH;
    float* out2 = out1 + H_DIM;
    float* out3 = out2 + NH * HS * HS;

    float* F = (float*)d_ws;
    float* xn   = F;                          // dead after mix; reused as as_s
    float* as_s = F;
    float* rb   = F + (size_t)1 * TH;
    float* kb   = F + (size_t)2 * TH;
    float* vb   = F + (size_t)3 * TH;
    float* ab   = F + (size_t)4 * TH;
    float* wpre = F + (size_t)5 * TH;
    float* vresb= F + (size_t)6 * TH;
    float* gb   = F + (size_t)7 * TH;
    float* yb   = F + (size_t)8 * TH;
    bf16* B = (bf16*)(F + (size_t)9 * TH);
    bf16 *xrb = B, *xwb = B + (size_t)TH, *xkb = B + (size_t)2 * TH,
         *xvb = B + (size_t)3 * TH, *xab = B + (size_t)4 * TH, *xgb = B + (size_t)5 * TH;
    bf16* Wrb = B + (size_t)6 * TH;
    bf16* Wkb = Wrb + (size_t)HH;
    bf16* Wvb = Wkb + (size_t)HH;
    bf16* Wob = Wvb + (size_t)HH;
    bf16* pp = Wob + (size_t)HH;
    bf16* a1T = pp; pp += (size_t)H_DIM * 64;
    bf16* w1T = pp; pp += (size_t)H_DIM * 64;
    bf16* v1T = pp; pp += (size_t)H_DIM * 32;
    bf16* g1T = pp; pp += (size_t)H_DIM * 128;
    bf16* a2T = pp; pp += (size_t)H_DIM * 64;
    bf16* w2T = pp; pp += (size_t)H_DIM * 64;
    bf16* v2T = pp; pp += (size_t)H_DIM * 32;
    bf16* g2T = pp; pp += (size_t)H_DIM * 128;
    bf16* amid = pp; pp += (size_t)T_TOK * 64;
    bf16* wmid = pp; pp += (size_t)T_TOK * 64;
    bf16* vmid = pp; pp += (size_t)T_TOK * 32;
    bf16* gmid = pp; pp += (size_t)T_TOK * 128;
    bf16* ybig = pp; pp += (size_t)TH;

    // 1. cast big weights to bf16
    CastPar cp;
    cp.src[0] = W_r; cp.src[1] = W_k; cp.src[2] = W_v; cp.src[3] = W_o;
    cp.dst[0] = Wrb; cp.dst[1] = Wkb; cp.dst[2] = Wvb; cp.dst[3] = Wob;
    castw_kernel<<<dim3(HH / 4 / 256, 1, 4), 256, 0, stream>>>(cp);

    // 2. transpose + cast small weights
    TPar tp;
    tp.src[0] = a1; tp.dst[0] = a1T; tp.R[0] = H_DIM; tp.C[0] = 64;
    tp.src[1] = w1; tp.dst[1] = w1T; tp.R[1] = H_DIM; tp.C[1] = 64;
    tp.src[2] = v1; tp.dst[2] = v1T; tp.R[2] = H_DIM; tp.C[2] = 32;
    tp.src[3] = g1; tp.dst[3] = g1T; tp.R[3] = H_DIM; tp.C[3] = 128;
    tp.src[4] = a2; tp.dst[4] = a2T; tp.R[4] = 64;  tp.C[4] = H_DIM;
    tp.src[5] = w2; tp.dst[5] = w2T; tp.R[5] = 64;  tp.C[5] = H_DIM;
    tp.src[6] = v2; tp.dst[6] = v2T; tp.R[6] = 32;  tp.C[6] = H_DIM;
    tp.src[7] = g2; tp.dst[7] = g2T; tp.R[7] = 128; tp.C[7] = H_DIM;
    transpose_kernel<<<dim3((H_DIM * 128 + 255) / 256, 1, 8), 256, 0, stream>>>(tp);

    // 3. LayerNorm
    ln_kernel<<<dim3(T_TOK), 256, 0, stream>>>(x, ln1_w, ln1_b, xn, out1);

    // 4. token-shift mixes
    MixPar mp; mp.xn = xn; mp.state1 = state1;
    mp.mv[0] = x_r; mp.mv[1] = x_w; mp.mv[2] = x_k; mp.mv[3] = x_v; mp.mv[4] = x_a; mp.mv[5] = x_g;
    mp.out[0] = xrb; mp.out[1] = xwb; mp.out[2] = xkb; mp.out[3] = xvb; mp.out[4] = xab; mp.out[5] = xgb;
    mix_kernel<<<dim3(T_TOK), 256, 0, stream>>>(mp);

    // 5. r,k,v GEMMs (async-staged big-GEMM)
    BGPar bp{};
    bp.X[0] = xrb; bp.W[0] = Wrb; bp.out[0] = rb; bp.resid[0] = nullptr;
    bp.X[1] = xkb; bp.W[1] = Wkb; bp.out[1] = kb; bp.resid[1] = nullptr;
    bp.X[2] = xvb; bp.W[2] = Wvb; bp.out[2] = vb; bp.resid[2] = nullptr;
    bgemm_kernel<<<dim3(16, 8, 3), 256, 0, stream>>>(bp);

    // 6. low-rank stage 1
    GPar s1{}; s1.M = T_TOK;
    s1.X[0] = xab; s1.W[0] = a1T; s1.outB[0] = amid; s1.N[0] = 64;  s1.K[0] = H_DIM; s1.act[0] = 0;
    s1.X[1] = xwb; s1.W[1] = w1T; s1.outB[1] = wmid; s1.N[1] = 64;  s1.K[1] = H_DIM; s1.act[1] = 2;
    s1.X[2] = xvb; s1.W[2] = v1T; s1.outB[2] = vmid; s1.N[2] = 32;  s1.K[2] = H_DIM; s1.act[2] = 0;
    s1.X[3] = xgb; s1.W[3] = g1T; s1.outB[3] = gmid; s1.N[3] = 128; s1.K[3] = H_DIM; s1.act[3] = 1;
    gemm_z_kernel<<<dim3(1, 8, 4), 256, 0, stream>>>(s1);

    // 7. low-rank stage 2
    GPar s2{}; s2.M = T_TOK;
    s2.X[0] = amid; s2.W[0] = a2T; s2.outF[0] = ab;    s2.N[0] = H_DIM; s2.K[0] = 64;  s2.act[0] = 1; s2.bias[0] = a0;
    s2.X[1] = wmid; s2.W[1] = w2T; s2.outF[1] = wpre;  s2.N[1] = H_DIM; s2.K[1] = 64;  s2.act[1] = 0;
    s2.X[2] = vmid; s2.W[2] = v2T; s2.outF[2] = vresb; s2.N[2] = H_DIM; s2.K[2] = 32;  s2.act[2] = 1; s2.bias[2] = v0;
    s2.X[3] = gmid; s2.W[3] = g2T; s2.outF[3] = gb;    s2.N[3] = H_DIM; s2.K[3] = 128; s2.act[3] = 0;
    gemm_z_kernel<<<dim3(16, 8, 4), 256, 0, stream>>>(s2);

    // 8. elementwise prep
    prep_kernel<<<dim3(NH, T_TOK), 64, 0, stream>>>(kb, vb, vfirst, vresb, wpre, ab, as_s, k_k, k_a, w0);

    // 9. scan (2 ILP chains per wave, 256 waves)
    scan_kernel<<<dim3(NH, 8), 64, 0, stream>>>(wpre, kb, vb, as_s, ab, rb, state2, yb, out2);

    // 10. groupnorm + bonus + gate
    post_kernel<<<dim3(NH, T_TOK), 64, 0, stream>>>(yb, rb, kb, vb, gb, r_k, ln_x_w, ln_x_b, ybig);

    // 11. final GEMM with residual
    BGPar bo{};
    bo.X[0] = ybig; bo.W[0] = Wob; bo.out[0] = out0; bo.resid[0] = x;
    bgemm_kernel<<<dim3(16, 8, 1), 256, 0, stream>>>(bo);

    // 12. v_first passthrough
    hipMemcpyAsync(out3, (const void*)vfirst, (size_t)TH * sizeof(float),
                   hipMemcpyDeviceToDevice, stream);
}

// Round 4
// 780.199 us; speedup vs baseline: 1.1201x; 1.1201x over previous
//
#include <hip/hip_runtime.h>
#include <hip/hip_bf16.h>
#include <cstdint>
#include <cstddef>

#define T_TOK 1024
#define H_DIM 2048
#define NH 32
#define HS 64
#define TH (T_TOK * H_DIM)
#define HH (H_DIM * H_DIM)

using short8 = __attribute__((ext_vector_type(8))) short;
using f32x4  = __attribute__((ext_vector_type(4))) float;
typedef __hip_bfloat16 bf16;

__device__ __forceinline__ float sigmoidf_(float x) { return 1.0f / (1.0f + expf(-x)); }

__device__ __forceinline__ float wsum64(float v) {
#pragma unroll
    for (int m = 32; m; m >>= 1) v += __shfl_xor(v, m, 64);
    return v;
}

// ---------------- cast big weights fp32 -> bf16 ----------------
struct CastPar { const float* src[4]; bf16* dst[4]; };
__global__ __launch_bounds__(256) void castw_kernel(CastPar p) {
    int z = blockIdx.z;
    const float4* s = (const float4*)p.src[z];
    bf16* d = p.dst[z];
    int i = blockIdx.x * 256 + threadIdx.x;
    float4 v = s[i];
    int b = i * 4;
    d[b + 0] = __float2bfloat16(v.x);
    d[b + 1] = __float2bfloat16(v.y);
    d[b + 2] = __float2bfloat16(v.z);
    d[b + 3] = __float2bfloat16(v.w);
}

// ---------------- transpose + cast small weights ----------------
struct TPar { const float* src[8]; bf16* dst[8]; int R[8]; int C[8]; };
__global__ __launch_bounds__(256) void transpose_kernel(TPar p) {
    int z = blockIdx.z;
    int R = p.R[z], C = p.C[z];
    int e = blockIdx.x * 256 + threadIdx.x;
    if (e >= R * C) return;
    int r = e / C, c = e % C;
    p.dst[z][(size_t)c * R + r] = __float2bfloat16(p.src[z][e]);
}

// ---------------- LayerNorm (ln1) ----------------
__global__ __launch_bounds__(256) void ln_kernel(const float* __restrict__ x,
                                                 const float* __restrict__ w,
                                                 const float* __restrict__ b,
                                                 float* __restrict__ xn,
                                                 float* __restrict__ s1out) {
    int t = blockIdx.x, tid = threadIdx.x;
    const float* xt = x + (size_t)t * H_DIM;
    float v[8]; float s = 0.f, s2 = 0.f;
#pragma unroll
    for (int e = 0; e < 8; e++) { v[e] = xt[tid + 256 * e]; s += v[e]; s2 += v[e] * v[e]; }
    s = wsum64(s); s2 = wsum64(s2);
    __shared__ float ls[8];
    int wid = tid >> 6, ln = tid & 63;
    if (ln == 0) { ls[wid] = s; ls[4 + wid] = s2; }
    __syncthreads();
    s = ls[0] + ls[1] + ls[2] + ls[3];
    s2 = ls[4] + ls[5] + ls[6] + ls[7];
    float mu = s * (1.f / H_DIM);
    float var = s2 * (1.f / H_DIM) - mu * mu;
    float inv = rsqrtf(var + 1e-5f);
#pragma unroll
    for (int e = 0; e < 8; e++) {
        int h = tid + 256 * e;
        float o = (v[e] - mu) * inv * w[h] + b[h];
        xn[(size_t)t * H_DIM + h] = o;
        if (t == T_TOK - 1) s1out[h] = o;
    }
}

// ---------------- token-shift mixes ----------------
struct MixPar { const float* xn; const float* state1; const float* mv[6]; bf16* out[6]; };
__global__ __launch_bounds__(256) void mix_kernel(MixPar p) {
    int t = blockIdx.x, tid = threadIdx.x;
#pragma unroll
    for (int e = 0; e < 8; e++) {
        int h = tid + 256 * e;
        size_t idx = (size_t)t * H_DIM + h;
        float cur = p.xn[idx];
        float prev = (t == 0) ? p.state1[h] : p.xn[idx - H_DIM];
        float sx = prev - cur;
#pragma unroll
        for (int q = 0; q < 6; q++)
            p.out[q][idx] = __float2bfloat16(cur + p.mv[q][h] * sx);
    }
}

// ======== big GEMM (M=1024, N=2048, K=2048): global_load_lds staging ========
typedef const __attribute__((address_space(1))) uint32_t* gp1_t;
typedef __attribute__((address_space(3))) uint32_t* lp3_t;
__device__ __forceinline__ void async16(const bf16* g, short* l) {
    __builtin_amdgcn_global_load_lds((gp1_t)g, (lp3_t)l, 16, 0, 0);
}

struct BGPar { const bf16* X[4]; const bf16* W[4]; float* out[4]; const float* resid[4]; };
__global__ __launch_bounds__(256) void bgemm_kernel(BGPar p) {
    int z = blockIdx.z;
    const bf16* __restrict__ X = p.X[z];
    const bf16* __restrict__ W = p.W[z];
    float* __restrict__ out = p.out[z];
    const float* __restrict__ resid = p.resid[z];

    __shared__ short As[128 * 32];
    __shared__ short Bs[128 * 32];

    int m0 = blockIdx.y * 128, n0 = blockIdx.x * 128;
    int tid = threadIdx.x, lane = tid & 63, wv = tid >> 6;
    int m_off = (wv >> 1) * 64, n_off = (wv & 1) * 64;
    int lr = lane & 15, lq = lane >> 4;

    int srow = lane >> 2;
    int scol = (lane & 3) * 8;
    const bf16* Ag0 = X + (size_t)(m0 + wv * 32 + srow) * 2048 + scol;
    const bf16* Ag1 = Ag0 + (size_t)16 * 2048;
    const bf16* Bg0 = W + (size_t)(n0 + wv * 32 + srow) * 2048 + scol;
    const bf16* Bg1 = Bg0 + (size_t)16 * 2048;
    short* Al0 = &As[(wv * 32) * 32];
    short* Al1 = &As[(wv * 32 + 16) * 32];
    short* Bl0 = &Bs[(wv * 32) * 32];
    short* Bl1 = &Bs[(wv * 32 + 16) * 32];

    f32x4 acc[4][4];
#pragma unroll
    for (int a = 0; a < 4; a++)
#pragma unroll
        for (int b = 0; b < 4; b++)
#pragma unroll
            for (int r = 0; r < 4; r++) acc[a][b][r] = 0.f;

    for (int k0 = 0; k0 < 2048; k0 += 32) {
        async16(Ag0 + k0, Al0);
        async16(Ag1 + k0, Al1);
        async16(Bg0 + k0, Bl0);
        async16(Bg1 + k0, Bl1);
        __syncthreads();
        short8 af[4], bfr[4];
#pragma unroll
        for (int mi = 0; mi < 4; mi++)
            af[mi] = *(const short8*)&As[(m_off + mi * 16 + lr) * 32 + lq * 8];
#pragma unroll
        for (int ni = 0; ni < 4; ni++)
            bfr[ni] = *(const short8*)&Bs[(n_off + ni * 16 + lr) * 32 + lq * 8];
#pragma unroll
        for (int mi = 0; mi < 4; mi++)
#pragma unroll
            for (int ni = 0; ni < 4; ni++)
                acc[mi][ni] = __builtin_amdgcn_mfma_f32_16x16x32_bf16(af[mi], bfr[ni], acc[mi][ni], 0, 0, 0);
        __syncthreads();
    }
#pragma unroll
    for (int mi = 0; mi < 4; mi++)
#pragma unroll
        for (int ni = 0; ni < 4; ni++)
#pragma unroll
            for (int r = 0; r < 4; r++) {
                int rowg = m0 + m_off + mi * 16 + lq * 4 + r;
                int colg = n0 + n_off + ni * 16 + lr;
                size_t o = (size_t)rowg * 2048 + colg;
                float v = acc[mi][ni][r];
                if (resid) v += resid[o];
                out[o] = v;
            }
}

// ---------------- generic small-GEMM ----------------
#define BM 128
#define BN 128
#define BK 32
#define LDK 40

__device__ __forceinline__ void gemm_core(const bf16* __restrict__ X, const bf16* __restrict__ W,
                                          int M, int N, int K, int act,
                                          const float* __restrict__ bias,
                                          float* __restrict__ outF, bf16* __restrict__ outB) {
    __shared__ short As[BM * LDK];
    __shared__ short Bs[BN * LDK];
    int m0 = blockIdx.y * BM, n0 = blockIdx.x * BN;
    if (n0 >= N) return;
    int tid = threadIdx.x;
    int lane = tid & 63, wid = tid >> 6;
    int m_off = (wid >> 1) * 64, n_off = (wid & 1) * 64;
    int lr = lane & 15, lq = lane >> 4;

    f32x4 acc[4][4];
#pragma unroll
    for (int a = 0; a < 4; a++)
#pragma unroll
        for (int b = 0; b < 4; b++)
#pragma unroll
            for (int r = 0; r < 4; r++) acc[a][b][r] = 0.f;

    for (int k0 = 0; k0 < K; k0 += BK) {
#pragma unroll
        for (int it = 0; it < 2; it++) {
            int c = tid + it * 256;
            int r = c >> 2;
            int cc = (c & 3) * 8;
            uint4 va = *(const uint4*)(X + (size_t)(m0 + r) * K + k0 + cc);
            *(uint4*)&As[r * LDK + cc] = va;
            uint4 vb;
            if (n0 + r < N) vb = *(const uint4*)(W + (size_t)(n0 + r) * K + k0 + cc);
            else            vb = make_uint4(0u, 0u, 0u, 0u);
            *(uint4*)&Bs[r * LDK + cc] = vb;
        }
        __syncthreads();
        short8 af[4], bfr[4];
#pragma unroll
        for (int mi = 0; mi < 4; mi++)
            af[mi] = *(const short8*)&As[(m_off + mi * 16 + lr) * LDK + lq * 8];
#pragma unroll
        for (int ni = 0; ni < 4; ni++)
            bfr[ni] = *(const short8*)&Bs[(n_off + ni * 16 + lr) * LDK + lq * 8];
#pragma unroll
        for (int mi = 0; mi < 4; mi++)
#pragma unroll
            for (int ni = 0; ni < 4; ni++)
                acc[mi][ni] = __builtin_amdgcn_mfma_f32_16x16x32_bf16(af[mi], bfr[ni], acc[mi][ni], 0, 0, 0);
        __syncthreads();
    }
#pragma unroll
    for (int mi = 0; mi < 4; mi++)
#pragma unroll
        for (int ni = 0; ni < 4; ni++)
#pragma unroll
            for (int r = 0; r < 4; r++) {
                int rowg = m0 + m_off + mi * 16 + lq * 4 + r;
                int colg = n0 + n_off + ni * 16 + lr;
                if (colg < N) {
                    float v = acc[mi][ni][r];
                    if (bias) v += bias[colg];
                    if (act == 1) v = sigmoidf_(v);
                    else if (act == 2) v = tanhf(v);
                    size_t o = (size_t)rowg * N + colg;
                    if (outF) outF[o] = v;
                    else      outB[o] = __float2bfloat16(v);
                }
            }
}

struct GPar {
    const bf16* X[4]; const bf16* W[4];
    float* outF[4]; bf16* outB[4];
    const float* bias[4];
    int N[4]; int K[4]; int act[4]; int M;
};
__global__ __launch_bounds__(256) void gemm_z_kernel(GPar p) {
    int z = blockIdx.z;
    gemm_core(p.X[z], p.W[z], p.M, p.N[z], p.K[z], p.act[z], p.bias[z], p.outF[z], p.outB[z]);
}

// ---------------- elementwise prep for the scan ----------------
__global__ __launch_bounds__(64) void prep_kernel(float* __restrict__ k_io, float* __restrict__ v_io,
                                                  const float* __restrict__ v_first,
                                                  const float* __restrict__ vres,
                                                  float* __restrict__ w_io, float* __restrict__ a_io,
                                                  float* __restrict__ as_out,
                                                  const float* __restrict__ k_k,
                                                  const float* __restrict__ k_a,
                                                  const float* __restrict__ w0) {
    int h = blockIdx.x, t = blockIdx.y, i = threadIdx.x;
    int hi = h * HS + i;
    size_t idx = (size_t)t * H_DIM + hi;
    float kf = k_io[idx];
    float kk = kf * k_k[hi];
    float ss = wsum64(kk * kk);
    float kkn = kk / (sqrtf(ss) + 1e-12f);
    float a = a_io[idx];
    k_io[idx] = kf * (1.f + (a - 1.f) * k_a[hi]);
    float vv = v_io[idx];
    v_io[idx] = vv + (v_first[idx] - vv) * vres[idx];
    w_io[idx] = expf(-0.606531f * sigmoidf_(w0[hi] + w_io[idx]));
    a_io[idx] = kkn * a;     // b_seq
    as_out[idx] = -kkn;      // a_seq
}

// ---------------- WKV7 scan: round-2 layout + inline-asm deep pipeline ----------------
// Wave (h,q) owns rows q*8..q*8+7. Lane il*8+jb holds S[q*8+il][jb*8..+8).
// j-reduction = 3 shfl_xor (lane bits 0-2). ALL loop VMEM is inline asm:
// 11 loads/step issued 4 steps ahead into explicit register slots, consumed
// after a manual `s_waitcnt vmcnt(33)` (= 3 slots x 11 loads younger; vmcnt
// retires in-order so this exactly waits for the consumed slot). Empty "+v"
// pin asm after the wait stops the compute from hoisting above it. The
// y-store is asm too (all 8 duplicate lanes store the same value) so the
// compiler tracks no VMEM in the loop and cannot inject vmcnt(0) drains.
struct SlotV { f32x4 w0, w1, a0, a1, b0, b1, k0, k1, r0, r1; float v; };

#define SCAN_ISSUE(sl, tt)                                                              \
    do {                                                                                \
        int tc_ = (tt) < T_TOK ? (tt) : T_TOK - 1;                                      \
        const float* wp_ = w_s + (size_t)tc_ * H_DIM + hb;                              \
        const float* ap_ = as_s + (size_t)tc_ * H_DIM + hb;                             \
        const float* bp_ = b_s + (size_t)tc_ * H_DIM + hb;                              \
        const float* kp_ = k_s + (size_t)tc_ * H_DIM + hb;                              \
        const float* rp_ = r_s + (size_t)tc_ * H_DIM + hb;                              \
        const float* vp_ = v_s + (size_t)tc_ * H_DIM + hb;                              \
        asm volatile("global_load_dwordx4 %0, %1, %2" : "=v"((sl).w0) : "v"(jow), "s"(wp_)); \
        asm volatile("global_load_dwordx4 %0, %1, %2 offset:16" : "=v"((sl).w1) : "v"(jow), "s"(wp_)); \
        asm volatile("global_load_dwordx4 %0, %1, %2" : "=v"((sl).a0) : "v"(jow), "s"(ap_)); \
        asm volatile("global_load_dwordx4 %0, %1, %2 offset:16" : "=v"((sl).a1) : "v"(jow), "s"(ap_)); \
        asm volatile("global_load_dwordx4 %0, %1, %2" : "=v"((sl).b0) : "v"(jow), "s"(bp_)); \
        asm volatile("global_load_dwordx4 %0, %1, %2 offset:16" : "=v"((sl).b1) : "v"(jow), "s"(bp_)); \
        asm volatile("global_load_dwordx4 %0, %1, %2" : "=v"((sl).k0) : "v"(jow), "s"(kp_)); \
        asm volatile("global_load_dwordx4 %0, %1, %2 offset:16" : "=v"((sl).k1) : "v"(jow), "s"(kp_)); \
        asm volatile("global_load_dwordx4 %0, %1, %2" : "=v"((sl).r0) : "v"(jow), "s"(rp_)); \
        asm volatile("global_load_dwordx4 %0, %1, %2 offset:16" : "=v"((sl).r1) : "v"(jow), "s"(rp_)); \
        asm volatile("global_load_dword %0, %1, %2" : "=v"((sl).v) : "v"(rowoff), "s"(vp_)); \
    } while (0)

#define SCAN_PIN(sl)                                                                    \
    asm volatile("" : "+v"((sl).w0), "+v"((sl).w1), "+v"((sl).a0), "+v"((sl).a1),       \
                      "+v"((sl).b0), "+v"((sl).b1), "+v"((sl).k0), "+v"((sl).k1),       \
                      "+v"((sl).r0), "+v"((sl).r1), "+v"((sl).v))

__global__ __launch_bounds__(64) void scan_kernel(const float* __restrict__ w_s,
                                                  const float* __restrict__ k_s,
                                                  const float* __restrict__ v_s,
                                                  const float* __restrict__ as_s,
                                                  const float* __restrict__ b_s,
                                                  const float* __restrict__ r_s,
                                                  const float* __restrict__ s2in,
                                                  float* __restrict__ y,
                                                  float* __restrict__ s2out) {
    int h = blockIdx.x, q = blockIdx.y;
    int lane = threadIdx.x;
    int il = lane >> 3, jb = lane & 7;
    int row = q * 8 + il;
    int jo = jb * 8;
    int hb = h * HS;
    int jow = jo * 4;       // byte offset for the 8-float vector slice
    int rowoff = row * 4;   // byte offset for v load / y store

    float S[8];
    {
        const float* s0 = s2in + (size_t)h * HS * HS + (size_t)row * HS + jo;
        float4 t0 = *(const float4*)s0, t1 = *(const float4*)(s0 + 4);
        S[0] = t0.x; S[1] = t0.y; S[2] = t0.z; S[3] = t0.w;
        S[4] = t1.x; S[5] = t1.y; S[6] = t1.z; S[7] = t1.w;
    }

    SlotV sv[4];
    SCAN_ISSUE(sv[0], 0);
    SCAN_ISSUE(sv[1], 1);
    SCAN_ISSUE(sv[2], 2);
    SCAN_ISSUE(sv[3], 3);

    for (int tb = 0; tb < T_TOK; tb += 4) {
#pragma unroll
        for (int d = 0; d < 4; d++) {
            int t = tb + d;
            asm volatile("s_waitcnt vmcnt(33)");
            SCAN_PIN(sv[d]);
            float sa = 0.f;
#pragma unroll
            for (int e = 0; e < 4; e++) {
                S[e]     *= sv[d].w0[e]; sa = fmaf(S[e],     sv[d].a0[e], sa);
                S[4 + e] *= sv[d].w1[e]; sa = fmaf(S[4 + e], sv[d].a1[e], sa);
            }
            sa += __shfl_xor(sa, 1, 64);
            sa += __shfl_xor(sa, 2, 64);
            sa += __shfl_xor(sa, 4, 64);
            float o = 0.f;
#pragma unroll
            for (int e = 0; e < 4; e++) {
                S[e]     = fmaf(sa, sv[d].b0[e], fmaf(sv[d].v, sv[d].k0[e], S[e]));     o = fmaf(S[e],     sv[d].r0[e], o);
                S[4 + e] = fmaf(sa, sv[d].b1[e], fmaf(sv[d].v, sv[d].k1[e], S[4 + e])); o = fmaf(S[4 + e], sv[d].r1[e], o);
            }
            o += __shfl_xor(o, 1, 64);
            o += __shfl_xor(o, 2, 64);
            o += __shfl_xor(o, 4, 64);
            {
                const float* yp_ = y + (size_t)t * H_DIM + hb;
                asm volatile("global_store_dword %0, %1, %2" :: "v"(rowoff), "v"(o), "s"(yp_) : "memory");
            }
            SCAN_ISSUE(sv[d], t + 4);
        }
    }

    {
        float* so = s2out + (size_t)h * HS * HS + (size_t)row * HS + jo;
        float4 t0, t1;
        t0.x = S[0]; t0.y = S[1]; t0.z = S[2]; t0.w = S[3];
        t1.x = S[4]; t1.y = S[5]; t1.z = S[6]; t1.w = S[7];
        *(float4*)so = t0; *(float4*)(so + 4) = t1;
    }
}

// ---------------- groupnorm + bonus + gate -> bf16 ----------------
__global__ __launch_bounds__(64) void post_kernel(const float* __restrict__ y,
                                                  const float* __restrict__ r_s,
                                                  const float* __restrict__ k_s,
                                                  const float* __restrict__ v_s,
                                                  const float* __restrict__ g_s,
                                                  const float* __restrict__ r_k,
                                                  const float* __restrict__ lnw,
                                                  const float* __restrict__ lnb,
                                                  bf16* __restrict__ ybig) {
    int h = blockIdx.x, t = blockIdx.y, i = threadIdx.x;
    int hi = h * HS + i;
    size_t idx = (size_t)t * H_DIM + hi;
    float yv = y[idx];
    float mu = wsum64(yv) * (1.f / HS);
    float d = yv - mu;
    float var = wsum64(d * d) * (1.f / HS);
    float yn = d * rsqrtf(var + 0.00064f);
    float bd = wsum64(r_s[idx] * k_s[idx] * r_k[hi]);
    float val = (yn * lnw[hi] + lnb[hi] + bd * v_s[idx]) * g_s[idx];
    ybig[idx] = __float2bfloat16(val);
}

// ---------------- launcher ----------------
extern "C" void kernel_launch(void* const* d_in, const int* in_sizes, int n_in,
                              void* d_out, int out_size, void* d_ws, size_t ws_size,
                              hipStream_t stream) {
    const float* x      = (const float*)d_in[0];
    const float* state1 = (const float*)d_in[1];
    const float* state2 = (const float*)d_in[2];
    const float* vfirst = (const float*)d_in[3];
    const float* x_r = (const float*)d_in[4];
    const float* x_w = (const float*)d_in[5];
    const float* x_k = (const float*)d_in[6];
    const float* x_v = (const float*)d_in[7];
    const float* x_a = (const float*)d_in[8];
    const float* x_g = (const float*)d_in[9];
    const float* W_r = (const float*)d_in[10];
    const float* W_k = (const float*)d_in[11];
    const float* W_v = (const float*)d_in[12];
    const float* W_o = (const float*)d_in[13];
    const float* w0 = (const float*)d_in[14];
    const float* w1 = (const float*)d_in[15];
    const float* w2 = (const float*)d_in[16];
    const float* a0 = (const float*)d_in[17];
    const float* a1 = (const float*)d_in[18];
    const float* a2 = (const float*)d_in[19];
    const float* v0 = (const float*)d_in[20];
    const float* v1 = (const float*)d_in[21];
    const float* v2 = (const float*)d_in[22];
    const float* g1 = (const float*)d_in[23];
    const float* g2 = (const float*)d_in[24];
    const float* k_k = (const float*)d_in[25];
    const float* k_a = (const float*)d_in[26];
    const float* r_k = (const float*)d_in[27];
    const float* ln_x_w = (const float*)d_in[28];
    const float* ln_x_b = (const float*)d_in[29];
    const float* ln1_w = (const float*)d_in[30];
    const float* ln1_b = (const float*)d_in[31];

    float* out0 = (float*)d_out;
    float* out1 = out0 + TH;
    float* out2 = out1 + H_DIM;
    float* out3 = out2 + NH * HS * HS;

    float* F = (float*)d_ws;
    float* xn   = F;                          // dead after mix; reused as as_s
    float* as_s = F;
    float* rb   = F + (size_t)1 * TH;
    float* kb   = F + (size_t)2 * TH;
    float* vb   = F + (size_t)3 * TH;
    float* ab   = F + (size_t)4 * TH;
    float* wpre = F + (size_t)5 * TH;
    float* vresb= F + (size_t)6 * TH;
    float* gb   = F + (size_t)7 * TH;
    float* yb   = F + (size_t)8 * TH;
    bf16* B = (bf16*)(F + (size_t)9 * TH);
    bf16 *xrb = B, *xwb = B + (size_t)TH, *xkb = B + (size_t)2 * TH,
         *xvb = B + (size_t)3 * TH, *xab = B + (size_t)4 * TH, *xgb = B + (size_t)5 * TH;
    bf16* Wrb = B + (size_t)6 * TH;
    bf16* Wkb = Wrb + (size_t)HH;
    bf16* Wvb = Wkb + (size_t)HH;
    bf16* Wob = Wvb + (size_t)HH;
    bf16* pp = Wob + (size_t)HH;
    bf16* a1T = pp; pp += (size_t)H_DIM * 64;
    bf16* w1T = pp; pp += (size_t)H_DIM * 64;
    bf16* v1T = pp; pp += (size_t)H_DIM * 32;
    bf16* g1T = pp; pp += (size_t)H_DIM * 128;
    bf16* a2T = pp; pp += (size_t)H_DIM * 64;
    bf16* w2T = pp; pp += (size_t)H_DIM * 64;
    bf16* v2T = pp; pp += (size_t)H_DIM * 32;
    bf16* g2T = pp; pp += (size_t)H_DIM * 128;
    bf16* amid = pp; pp += (size_t)T_TOK * 64;
    bf16* wmid = pp; pp += (size_t)T_TOK * 64;
    bf16* vmid = pp; pp += (size_t)T_TOK * 32;
    bf16* gmid = pp; pp += (size_t)T_TOK * 128;
    bf16* ybig = pp; pp += (size_t)TH;

    // 1. cast big weights to bf16
    CastPar cp;
    cp.src[0] = W_r; cp.src[1] = W_k; cp.src[2] = W_v; cp.src[3] = W_o;
    cp.dst[0] = Wrb; cp.dst[1] = Wkb; cp.dst[2] = Wvb; cp.dst[3] = Wob;
    castw_kernel<<<dim3(HH / 4 / 256, 1, 4), 256, 0, stream>>>(cp);

    // 2. transpose + cast small weights
    TPar tp;
    tp.src[0] = a1; tp.dst[0] = a1T; tp.R[0] = H_DIM; tp.C[0] = 64;
    tp.src[1] = w1; tp.dst[1] = w1T; tp.R[1] = H_DIM; tp.C[1] = 64;
    tp.src[2] = v1; tp.dst[2] = v1T; tp.R[2] = H_DIM; tp.C[2] = 32;
    tp.src[3] = g1; tp.dst[3] = g1T; tp.R[3] = H_DIM; tp.C[3] = 128;
    tp.src[4] = a2; tp.dst[4] = a2T; tp.R[4] = 64;  tp.C[4] = H_DIM;
    tp.src[5] = w2; tp.dst[5] = w2T; tp.R[5] = 64;  tp.C[5] = H_DIM;
    tp.src[6] = v2; tp.dst[6] = v2T; tp.R[6] = 32;  tp.C[6] = H_DIM;
    tp.src[7] = g2; tp.dst[7] = g2T; tp.R[7] = 128; tp.C[7] = H_DIM;
    transpose_kernel<<<dim3((H_DIM * 128 + 255) / 256, 1, 8), 256, 0, stream>>>(tp);

    // 3. LayerNorm
    ln_kernel<<<dim3(T_TOK), 256, 0, stream>>>(x, ln1_w, ln1_b, xn, out1);

    // 4. token-shift mixes
    MixPar mp; mp.xn = xn; mp.state1 = state1;
    mp.mv[0] = x_r; mp.mv[1] = x_w; mp.mv[2] = x_k; mp.mv[3] = x_v; mp.mv[4] = x_a; mp.mv[5] = x_g;
    mp.out[0] = xrb; mp.out[1] = xwb; mp.out[2] = xkb; mp.out[3] = xvb; mp.out[4] = xab; mp.out[5] = xgb;
    mix_kernel<<<dim3(T_TOK), 256, 0, stream>>>(mp);

    // 5. r,k,v GEMMs
    BGPar bp{};
    bp.X[0] = xrb; bp.W[0] = Wrb; bp.out[0] = rb; bp.resid[0] = nullptr;
    bp.X[1] = xkb; bp.W[1] = Wkb; bp.out[1] = kb; bp.resid[1] = nullptr;
    bp.X[2] = xvb; bp.W[2] = Wvb; bp.out[2] = vb; bp.resid[2] = nullptr;
    bgemm_kernel<<<dim3(16, 8, 3), 256, 0, stream>>>(bp);

    // 6. low-rank stage 1
    GPar s1{}; s1.M = T_TOK;
    s1.X[0] = xab; s1.W[0] = a1T; s1.outB[0] = amid; s1.N[0] = 64;  s1.K[0] = H_DIM; s1.act[0] = 0;
    s1.X[1] = xwb; s1.W[1] = w1T; s1.outB[1] = wmid; s1.N[1] = 64;  s1.K[1] = H_DIM; s1.act[1] = 2;
    s1.X[2] = xvb; s1.W[2] = v1T; s1.outB[2] = vmid; s1.N[2] = 32;  s1.K[2] = H_DIM; s1.act[2] = 0;
    s1.X[3] = xgb; s1.W[3] = g1T; s1.outB[3] = gmid; s1.N[3] = 128; s1.K[3] = H_DIM; s1.act[3] = 1;
    gemm_z_kernel<<<dim3(1, 8, 4), 256, 0, stream>>>(s1);

    // 7. low-rank stage 2
    GPar s2{}; s2.M = T_TOK;
    s2.X[0] = amid; s2.W[0] = a2T; s2.outF[0] = ab;    s2.N[0] = H_DIM; s2.K[0] = 64;  s2.act[0] = 1; s2.bias[0] = a0;
    s2.X[1] = wmid; s2.W[1] = w2T; s2.outF[1] = wpre;  s2.N[1] = H_DIM; s2.K[1] = 64;  s2.act[1] = 0;
    s2.X[2] = vmid; s2.W[2] = v2T; s2.outF[2] = vresb; s2.N[2] = H_DIM; s2.K[2] = 32;  s2.act[2] = 1; s2.bias[2] = v0;
    s2.X[3] = gmid; s2.W[3] = g2T; s2.outF[3] = gb;    s2.N[3] = H_DIM; s2.K[3] = 128; s2.act[3] = 0;
    gemm_z_kernel<<<dim3(16, 8, 4), 256, 0, stream>>>(s2);

    // 8. elementwise prep
    prep_kernel<<<dim3(NH, T_TOK), 64, 0, stream>>>(kb, vb, vfirst, vresb, wpre, ab, as_s, k_k, k_a, w0);

    // 9. scan (asm-pipelined, 256 waves)
    scan_kernel<<<dim3(NH, 8), 64, 0, stream>>>(wpre, kb, vb, as_s, ab, rb, state2, yb, out2);

    // 10. groupnorm + bonus + gate
    post_kernel<<<dim3(NH, T_TOK), 64, 0, stream>>>(yb, rb, kb, vb, gb, r_k, ln_x_w, ln_x_b, ybig);

    // 11. final GEMM with residual
    BGPar bo{};
    bo.X[0] = ybig; bo.W[0] = Wob; bo.out[0] = out0; bo.resid[0] = x;
    bgemm_kernel<<<dim3(16, 8, 1), 256, 0, stream>>>(bo);

    // 12. v_first passthrough
    hipMemcpyAsync(out3, (const void*)vfirst, (size_t)TH * sizeof(float),
                   hipMemcpyDeviceToDevice, stream);
}

// Round 5
// 703.005 us; speedup vs baseline: 1.2431x; 1.1098x over previous
//
#include <hip/hip_runtime.h>
#include <hip/hip_bf16.h>
#include <cstdint>
#include <cstddef>

#define T_TOK 1024
#define H_DIM 2048
#define NH 32
#define HS 64
#define TH (T_TOK * H_DIM)
#define HH (H_DIM * H_DIM)

using short8 = __attribute__((ext_vector_type(8))) short;
using f32x4  = __attribute__((ext_vector_type(4))) float;
typedef __hip_bfloat16 bf16;

__device__ __forceinline__ float sigmoidf_(float x) { return 1.0f / (1.0f + expf(-x)); }

__device__ __forceinline__ float wsum64(float v) {
#pragma unroll
    for (int m = 32; m; m >>= 1) v += __shfl_xor(v, m, 64);
    return v;
}

// DPP sum over aligned 8-lane groups (lane bits 0..2) — pure VALU, no DS ops.
// quad_perm xor1 (0xB1), quad_perm xor2 (0x4E), then row_half_mirror (0x141):
// after the quad stages all 4 lanes of a quad hold the quad sum, so the
// half-row mirror (lane -> 7-lane within each 8) supplies the other quad.
__device__ __forceinline__ float dpp_add8(float x) {
    int t;
    t = __builtin_amdgcn_update_dpp(0, __float_as_int(x), 0xB1, 0xF, 0xF, true);
    x += __int_as_float(t);
    t = __builtin_amdgcn_update_dpp(0, __float_as_int(x), 0x4E, 0xF, 0xF, true);
    x += __int_as_float(t);
    t = __builtin_amdgcn_update_dpp(0, __float_as_int(x), 0x141, 0xF, 0xF, true);
    x += __int_as_float(t);
    return x;
}

// ---------------- cast big weights fp32 -> bf16 ----------------
struct CastPar { const float* src[4]; bf16* dst[4]; };
__global__ __launch_bounds__(256) void castw_kernel(CastPar p) {
    int z = blockIdx.z;
    const float4* s = (const float4*)p.src[z];
    bf16* d = p.dst[z];
    int i = blockIdx.x * 256 + threadIdx.x;
    float4 v = s[i];
    int b = i * 4;
    d[b + 0] = __float2bfloat16(v.x);
    d[b + 1] = __float2bfloat16(v.y);
    d[b + 2] = __float2bfloat16(v.z);
    d[b + 3] = __float2bfloat16(v.w);
}

// ---------------- transpose + cast small weights ----------------
struct TPar { const float* src[8]; bf16* dst[8]; int R[8]; int C[8]; };
__global__ __launch_bounds__(256) void transpose_kernel(TPar p) {
    int z = blockIdx.z;
    int R = p.R[z], C = p.C[z];
    int e = blockIdx.x * 256 + threadIdx.x;
    if (e >= R * C) return;
    int r = e / C, c = e % C;
    p.dst[z][(size_t)c * R + r] = __float2bfloat16(p.src[z][e]);
}

// ---------------- LayerNorm (ln1) ----------------
__global__ __launch_bounds__(256) void ln_kernel(const float* __restrict__ x,
                                                 const float* __restrict__ w,
                                                 const float* __restrict__ b,
                                                 float* __restrict__ xn,
                                                 float* __restrict__ s1out) {
    int t = blockIdx.x, tid = threadIdx.x;
    const float* xt = x + (size_t)t * H_DIM;
    float v[8]; float s = 0.f, s2 = 0.f;
#pragma unroll
    for (int e = 0; e < 8; e++) { v[e] = xt[tid + 256 * e]; s += v[e]; s2 += v[e] * v[e]; }
    s = wsum64(s); s2 = wsum64(s2);
    __shared__ float ls[8];
    int wid = tid >> 6, ln = tid & 63;
    if (ln == 0) { ls[wid] = s; ls[4 + wid] = s2; }
    __syncthreads();
    s = ls[0] + ls[1] + ls[2] + ls[3];
    s2 = ls[4] + ls[5] + ls[6] + ls[7];
    float mu = s * (1.f / H_DIM);
    float var = s2 * (1.f / H_DIM) - mu * mu;
    float inv = rsqrtf(var + 1e-5f);
#pragma unroll
    for (int e = 0; e < 8; e++) {
        int h = tid + 256 * e;
        float o = (v[e] - mu) * inv * w[h] + b[h];
        xn[(size_t)t * H_DIM + h] = o;
        if (t == T_TOK - 1) s1out[h] = o;
    }
}

// ---------------- token-shift mixes ----------------
struct MixPar { const float* xn; const float* state1; const float* mv[6]; bf16* out[6]; };
__global__ __launch_bounds__(256) void mix_kernel(MixPar p) {
    int t = blockIdx.x, tid = threadIdx.x;
#pragma unroll
    for (int e = 0; e < 8; e++) {
        int h = tid + 256 * e;
        size_t idx = (size_t)t * H_DIM + h;
        float cur = p.xn[idx];
        float prev = (t == 0) ? p.state1[h] : p.xn[idx - H_DIM];
        float sx = prev - cur;
#pragma unroll
        for (int q = 0; q < 6; q++)
            p.out[q][idx] = __float2bfloat16(cur + p.mv[q][h] * sx);
    }
}

// ======== big GEMM: double-buffered global_load_lds, raw barrier + vmcnt(4) ========
typedef const __attribute__((address_space(1))) uint32_t* gp1_t;
typedef __attribute__((address_space(3))) uint32_t* lp3_t;
__device__ __forceinline__ void async16(const bf16* g, short* l) {
    __builtin_amdgcn_global_load_lds((gp1_t)g, (lp3_t)l, 16, 0, 0);
}

struct BGPar { const bf16* X[4]; const bf16* W[4]; float* out[4]; const float* resid[4]; };
__global__ __launch_bounds__(256) void bgemm_kernel(BGPar p) {
    int z = blockIdx.z;
    const bf16* __restrict__ X = p.X[z];
    const bf16* __restrict__ W = p.W[z];
    float* __restrict__ out = p.out[z];
    const float* __restrict__ resid = p.resid[z];

    __shared__ short As[2][128 * 32];
    __shared__ short Bs[2][128 * 32];

    int m0 = blockIdx.y * 128, n0 = blockIdx.x * 128;
    int tid = threadIdx.x, lane = tid & 63, wv = tid >> 6;
    int m_off = (wv >> 1) * 64, n_off = (wv & 1) * 64;
    int lr = lane & 15, lq = lane >> 4;

    int srow = lane >> 2;
    int scol = (lane & 3) * 8;
    const bf16* Ag0 = X + (size_t)(m0 + wv * 32 + srow) * 2048 + scol;
    const bf16* Ag1 = Ag0 + (size_t)16 * 2048;
    const bf16* Bg0 = W + (size_t)(n0 + wv * 32 + srow) * 2048 + scol;
    const bf16* Bg1 = Bg0 + (size_t)16 * 2048;

    f32x4 acc[4][4];
#pragma unroll
    for (int a = 0; a < 4; a++)
#pragma unroll
        for (int b = 0; b < 4; b++)
#pragma unroll
            for (int r = 0; r < 4; r++) acc[a][b][r] = 0.f;

    // prologue: tile 0 -> buf 0
    async16(Ag0, &As[0][(wv * 32) * 32]);
    async16(Ag1, &As[0][(wv * 32 + 16) * 32]);
    async16(Bg0, &Bs[0][(wv * 32) * 32]);
    async16(Bg1, &Bs[0][(wv * 32 + 16) * 32]);

    int buf = 0;
    for (int k0 = 0; k0 < 2048; k0 += 32, buf ^= 1) {
        if (k0 + 32 < 2048) {
            int nb = buf ^ 1;
            async16(Ag0 + k0 + 32, &As[nb][(wv * 32) * 32]);
            async16(Ag1 + k0 + 32, &As[nb][(wv * 32 + 16) * 32]);
            async16(Bg0 + k0 + 32, &Bs[nb][(wv * 32) * 32]);
            async16(Bg1 + k0 + 32, &Bs[nb][(wv * 32 + 16) * 32]);
            asm volatile("s_waitcnt vmcnt(4)" ::: "memory");   // cur tile done, next stays in flight
        } else {
            asm volatile("s_waitcnt vmcnt(0)" ::: "memory");
        }
        asm volatile("s_barrier" ::: "memory");                // all waves' cur loads landed
        short8 af[4], bfr[4];
#pragma unroll
        for (int mi = 0; mi < 4; mi++)
            af[mi] = *(const short8*)&As[buf][(m_off + mi * 16 + lr) * 32 + lq * 8];
#pragma unroll
        for (int ni = 0; ni < 4; ni++)
            bfr[ni] = *(const short8*)&Bs[buf][(n_off + ni * 16 + lr) * 32 + lq * 8];
#pragma unroll
        for (int mi = 0; mi < 4; mi++)
#pragma unroll
            for (int ni = 0; ni < 4; ni++)
                acc[mi][ni] = __builtin_amdgcn_mfma_f32_16x16x32_bf16(af[mi], bfr[ni], acc[mi][ni], 0, 0, 0);
        asm volatile("s_barrier" ::: "memory");                // cur buf free for overwrite
    }
#pragma unroll
    for (int mi = 0; mi < 4; mi++)
#pragma unroll
        for (int ni = 0; ni < 4; ni++)
#pragma unroll
            for (int r = 0; r < 4; r++) {
                int rowg = m0 + m_off + mi * 16 + lq * 4 + r;
                int colg = n0 + n_off + ni * 16 + lr;
                size_t o = (size_t)rowg * 2048 + colg;
                float v = acc[mi][ni][r];
                if (resid) v += resid[o];
                out[o] = v;
            }
}

// ---------------- generic small-GEMM ----------------
#define BM 128
#define BN 128
#define BK 32
#define LDK 40

__device__ __forceinline__ void gemm_core(const bf16* __restrict__ X, const bf16* __restrict__ W,
                                          int M, int N, int K, int act,
                                          const float* __restrict__ bias,
                                          float* __restrict__ outF, bf16* __restrict__ outB) {
    __shared__ short As[BM * LDK];
    __shared__ short Bs[BN * LDK];
    int m0 = blockIdx.y * BM, n0 = blockIdx.x * BN;
    if (n0 >= N) return;
    int tid = threadIdx.x;
    int lane = tid & 63, wid = tid >> 6;
    int m_off = (wid >> 1) * 64, n_off = (wid & 1) * 64;
    int lr = lane & 15, lq = lane >> 4;

    f32x4 acc[4][4];
#pragma unroll
    for (int a = 0; a < 4; a++)
#pragma unroll
        for (int b = 0; b < 4; b++)
#pragma unroll
            for (int r = 0; r < 4; r++) acc[a][b][r] = 0.f;

    for (int k0 = 0; k0 < K; k0 += BK) {
#pragma unroll
        for (int it = 0; it < 2; it++) {
            int c = tid + it * 256;
            int r = c >> 2;
            int cc = (c & 3) * 8;
            uint4 va = *(const uint4*)(X + (size_t)(m0 + r) * K + k0 + cc);
            *(uint4*)&As[r * LDK + cc] = va;
            uint4 vb;
            if (n0 + r < N) vb = *(const uint4*)(W + (size_t)(n0 + r) * K + k0 + cc);
            else            vb = make_uint4(0u, 0u, 0u, 0u);
            *(uint4*)&Bs[r * LDK + cc] = vb;
        }
        __syncthreads();
        short8 af[4], bfr[4];
#pragma unroll
        for (int mi = 0; mi < 4; mi++)
            af[mi] = *(const short8*)&As[(m_off + mi * 16 + lr) * LDK + lq * 8];
#pragma unroll
        for (int ni = 0; ni < 4; ni++)
            bfr[ni] = *(const short8*)&Bs[(n_off + ni * 16 + lr) * LDK + lq * 8];
#pragma unroll
        for (int mi = 0; mi < 4; mi++)
#pragma unroll
            for (int ni = 0; ni < 4; ni++)
                acc[mi][ni] = __builtin_amdgcn_mfma_f32_16x16x32_bf16(af[mi], bfr[ni], acc[mi][ni], 0, 0, 0);
        __syncthreads();
    }
#pragma unroll
    for (int mi = 0; mi < 4; mi++)
#pragma unroll
        for (int ni = 0; ni < 4; ni++)
#pragma unroll
            for (int r = 0; r < 4; r++) {
                int rowg = m0 + m_off + mi * 16 + lq * 4 + r;
                int colg = n0 + n_off + ni * 16 + lr;
                if (colg < N) {
                    float v = acc[mi][ni][r];
                    if (bias) v += bias[colg];
                    if (act == 1) v = sigmoidf_(v);
                    else if (act == 2) v = tanhf(v);
                    size_t o = (size_t)rowg * N + colg;
                    if (outF) outF[o] = v;
                    else      outB[o] = __float2bfloat16(v);
                }
            }
}

struct GPar {
    const bf16* X[4]; const bf16* W[4];
    float* outF[4]; bf16* outB[4];
    const float* bias[4];
    int N[4]; int K[4]; int act[4]; int M;
};
__global__ __launch_bounds__(256) void gemm_z_kernel(GPar p) {
    int z = blockIdx.z;
    gemm_core(p.X[z], p.W[z], p.M, p.N[z], p.K[z], p.act[z], p.bias[z], p.outF[z], p.outB[z]);
}

// ---------------- elementwise prep for the scan ----------------
__global__ __launch_bounds__(64) void prep_kernel(float* __restrict__ k_io, float* __restrict__ v_io,
                                                  const float* __restrict__ v_first,
                                                  const float* __restrict__ vres,
                                                  float* __restrict__ w_io, float* __restrict__ a_io,
                                                  float* __restrict__ as_out,
                                                  const float* __restrict__ k_k,
                                                  const float* __restrict__ k_a,
                                                  const float* __restrict__ w0) {
    int h = blockIdx.x, t = blockIdx.y, i = threadIdx.x;
    int hi = h * HS + i;
    size_t idx = (size_t)t * H_DIM + hi;
    float kf = k_io[idx];
    float kk = kf * k_k[hi];
    float ss = wsum64(kk * kk);
    float kkn = kk / (sqrtf(ss) + 1e-12f);
    float a = a_io[idx];
    k_io[idx] = kf * (1.f + (a - 1.f) * k_a[hi]);
    float vv = v_io[idx];
    v_io[idx] = vv + (v_first[idx] - vv) * vres[idx];
    w_io[idx] = expf(-0.606531f * sigmoidf_(w0[hi] + w_io[idx]));
    a_io[idx] = kkn * a;     // b_seq
    as_out[idx] = -kkn;      // a_seq
}

// ---------------- WKV7 scan: asm load pipeline + DPP reductions ----------------
// Wave (h,q) owns rows q*8..q*8+7. Lane il*8+jb holds S[q*8+il][jb*8..+8).
// j-reduction = dpp_add8 (3 VALU DPP adds, NO DS ops — round-4 evidence shows
// __shfl_xor lowers to ~120-cyc DS ops and was 90% of step time).
// Loads: 11/step issued 4 steps ahead (asm, explicit slots), consumed after
// manual s_waitcnt vmcnt(33); pin asm stops hoisting. y-store in asm so the
// compiler tracks no VMEM in the loop.
struct SlotV { f32x4 w0, w1, a0, a1, b0, b1, k0, k1, r0, r1; float v; };

#define SCAN_ISSUE(sl, tt)                                                              \
    do {                                                                                \
        int tc_ = (tt) < T_TOK ? (tt) : T_TOK - 1;                                      \
        const float* wp_ = w_s + (size_t)tc_ * H_DIM + hb;                              \
        const float* ap_ = as_s + (size_t)tc_ * H_DIM + hb;                             \
        const float* bp_ = b_s + (size_t)tc_ * H_DIM + hb;                              \
        const float* kp_ = k_s + (size_t)tc_ * H_DIM + hb;                              \
        const float* rp_ = r_s + (size_t)tc_ * H_DIM + hb;                              \
        const float* vp_ = v_s + (size_t)tc_ * H_DIM + hb;                              \
        asm volatile("global_load_dwordx4 %0, %1, %2" : "=v"((sl).w0) : "v"(jow), "s"(wp_)); \
        asm volatile("global_load_dwordx4 %0, %1, %2 offset:16" : "=v"((sl).w1) : "v"(jow), "s"(wp_)); \
        asm volatile("global_load_dwordx4 %0, %1, %2" : "=v"((sl).a0) : "v"(jow), "s"(ap_)); \
        asm volatile("global_load_dwordx4 %0, %1, %2 offset:16" : "=v"((sl).a1) : "v"(jow), "s"(ap_)); \
        asm volatile("global_load_dwordx4 %0, %1, %2" : "=v"((sl).b0) : "v"(jow), "s"(bp_)); \
        asm volatile("global_load_dwordx4 %0, %1, %2 offset:16" : "=v"((sl).b1) : "v"(jow), "s"(bp_)); \
        asm volatile("global_load_dwordx4 %0, %1, %2" : "=v"((sl).k0) : "v"(jow), "s"(kp_)); \
        asm volatile("global_load_dwordx4 %0, %1, %2 offset:16" : "=v"((sl).k1) : "v"(jow), "s"(kp_)); \
        asm volatile("global_load_dwordx4 %0, %1, %2" : "=v"((sl).r0) : "v"(jow), "s"(rp_)); \
        asm volatile("global_load_dwordx4 %0, %1, %2 offset:16" : "=v"((sl).r1) : "v"(jow), "s"(rp_)); \
        asm volatile("global_load_dword %0, %1, %2" : "=v"((sl).v) : "v"(rowoff), "s"(vp_)); \
    } while (0)

#define SCAN_PIN(sl)                                                                    \
    asm volatile("" : "+v"((sl).w0), "+v"((sl).w1), "+v"((sl).a0), "+v"((sl).a1),       \
                      "+v"((sl).b0), "+v"((sl).b1), "+v"((sl).k0), "+v"((sl).k1),       \
                      "+v"((sl).r0), "+v"((sl).r1), "+v"((sl).v))

__global__ __launch_bounds__(64) void scan_kernel(const float* __restrict__ w_s,
                                                  const float* __restrict__ k_s,
                                                  const float* __restrict__ v_s,
                                                  const float* __restrict__ as_s,
                                                  const float* __restrict__ b_s,
                                                  const float* __restrict__ r_s,
                                                  const float* __restrict__ s2in,
                                                  float* __restrict__ y,
                                                  float* __restrict__ s2out) {
    int h = blockIdx.x, q = blockIdx.y;
    int lane = threadIdx.x;
    int il = lane >> 3, jb = lane & 7;
    int row = q * 8 + il;
    int jo = jb * 8;
    int hb = h * HS;
    int jow = jo * 4;
    int rowoff = row * 4;

    float S[8];
    {
        const float* s0 = s2in + (size_t)h * HS * HS + (size_t)row * HS + jo;
        float4 t0 = *(const float4*)s0, t1 = *(const float4*)(s0 + 4);
        S[0] = t0.x; S[1] = t0.y; S[2] = t0.z; S[3] = t0.w;
        S[4] = t1.x; S[5] = t1.y; S[6] = t1.z; S[7] = t1.w;
    }

    SlotV sv[4];
    SCAN_ISSUE(sv[0], 0);
    SCAN_ISSUE(sv[1], 1);
    SCAN_ISSUE(sv[2], 2);
    SCAN_ISSUE(sv[3], 3);

    for (int tb = 0; tb < T_TOK; tb += 4) {
#pragma unroll
        for (int d = 0; d < 4; d++) {
            int t = tb + d;
            asm volatile("s_waitcnt vmcnt(33)");
            SCAN_PIN(sv[d]);
            float sa0 = 0.f, sa1 = 0.f;
#pragma unroll
            for (int e = 0; e < 4; e++) {
                S[e]     *= sv[d].w0[e]; sa0 = fmaf(S[e],     sv[d].a0[e], sa0);
                S[4 + e] *= sv[d].w1[e]; sa1 = fmaf(S[4 + e], sv[d].a1[e], sa1);
            }
            float sa = dpp_add8(sa0 + sa1);
            float o0 = 0.f, o1 = 0.f;
#pragma unroll
            for (int e = 0; e < 4; e++) {
                S[e]     = fmaf(sa, sv[d].b0[e], fmaf(sv[d].v, sv[d].k0[e], S[e]));     o0 = fmaf(S[e],     sv[d].r0[e], o0);
                S[4 + e] = fmaf(sa, sv[d].b1[e], fmaf(sv[d].v, sv[d].k1[e], S[4 + e])); o1 = fmaf(S[4 + e], sv[d].r1[e], o1);
            }
            float o = dpp_add8(o0 + o1);
            {
                const float* yp_ = y + (size_t)t * H_DIM + hb;
                asm volatile("global_store_dword %0, %1, %2" :: "v"(rowoff), "v"(o), "s"(yp_) : "memory");
            }
            SCAN_ISSUE(sv[d], t + 4);
        }
    }
    // drain outstanding asm loads before the compiler reuses their registers
    asm volatile("s_waitcnt vmcnt(0)" ::: "memory");

    {
        float* so = s2out + (size_t)h * HS * HS + (size_t)row * HS + jo;
        float4 t0, t1;
        t0.x = S[0]; t0.y = S[1]; t0.z = S[2]; t0.w = S[3];
        t1.x = S[4]; t1.y = S[5]; t1.z = S[6]; t1.w = S[7];
        *(float4*)so = t0; *(float4*)(so + 4) = t1;
    }
}

// ---------------- groupnorm + bonus + gate -> bf16 ----------------
__global__ __launch_bounds__(64) void post_kernel(const float* __restrict__ y,
                                                  const float* __restrict__ r_s,
                                                  const float* __restrict__ k_s,
                                                  const float* __restrict__ v_s,
                                                  const float* __restrict__ g_s,
                                                  const float* __restrict__ r_k,
                                                  const float* __restrict__ lnw,
                                                  const float* __restrict__ lnb,
                                                  bf16* __restrict__ ybig) {
    int h = blockIdx.x, t = blockIdx.y, i = threadIdx.x;
    int hi = h * HS + i;
    size_t idx = (size_t)t * H_DIM + hi;
    float yv = y[idx];
    float mu = wsum64(yv) * (1.f / HS);
    float d = yv - mu;
    float var = wsum64(d * d) * (1.f / HS);
    float yn = d * rsqrtf(var + 0.00064f);
    float bd = wsum64(r_s[idx] * k_s[idx] * r_k[hi]);
    float val = (yn * lnw[hi] + lnb[hi] + bd * v_s[idx]) * g_s[idx];
    ybig[idx] = __float2bfloat16(val);
}

// ---------------- launcher ----------------
extern "C" void kernel_launch(void* const* d_in, const int* in_sizes, int n_in,
                              void* d_out, int out_size, void* d_ws, size_t ws_size,
                              hipStream_t stream) {
    const float* x      = (const float*)d_in[0];
    const float* state1 = (const float*)d_in[1];
    const float* state2 = (const float*)d_in[2];
    const float* vfirst = (const float*)d_in[3];
    const float* x_r = (const float*)d_in[4];
    const float* x_w = (const float*)d_in[5];
    const float* x_k = (const float*)d_in[6];
    const float* x_v = (const float*)d_in[7];
    const float* x_a = (const float*)d_in[8];
    const float* x_g = (const float*)d_in[9];
    const float* W_r = (const float*)d_in[10];
    const float* W_k = (const float*)d_in[11];
    const float* W_v = (const float*)d_in[12];
    const float* W_o = (const float*)d_in[13];
    const float* w0 = (const float*)d_in[14];
    const float* w1 = (const float*)d_in[15];
    const float* w2 = (const float*)d_in[16];
    const float* a0 = (const float*)d_in[17];
    const float* a1 = (const float*)d_in[18];
    const float* a2 = (const float*)d_in[19];
    const float* v0 = (const float*)d_in[20];
    const float* v1 = (const float*)d_in[21];
    const float* v2 = (const float*)d_in[22];
    const float* g1 = (const float*)d_in[23];
    const float* g2 = (const float*)d_in[24];
    const float* k_k = (const float*)d_in[25];
    const float* k_a = (const float*)d_in[26];
    const float* r_k = (const float*)d_in[27];
    const float* ln_x_w = (const float*)d_in[28];
    const float* ln_x_b = (const float*)d_in[29];
    const float* ln1_w = (const float*)d_in[30];
    const float* ln1_b = (const float*)d_in[31];

    float* out0 = (float*)d_out;
    float* out1 = out0 + TH;
    float* out2 = out1 + H_DIM;
    float* out3 = out2 + NH * HS * HS;

    float* F = (float*)d_ws;
    float* xn   = F;                          // dead after mix; reused as as_s
    float* as_s = F;
    float* rb   = F + (size_t)1 * TH;
    float* kb   = F + (size_t)2 * TH;
    float* vb   = F + (size_t)3 * TH;
    float* ab   = F + (size_t)4 * TH;
    float* wpre = F + (size_t)5 * TH;
    float* vresb= F + (size_t)6 * TH;
    float* gb   = F + (size_t)7 * TH;
    float* yb   = F + (size_t)8 * TH;
    bf16* B = (bf16*)(F + (size_t)9 * TH);
    bf16 *xrb = B, *xwb = B + (size_t)TH, *xkb = B + (size_t)2 * TH,
         *xvb = B + (size_t)3 * TH, *xab = B + (size_t)4 * TH, *xgb = B + (size_t)5 * TH;
    bf16* Wrb = B + (size_t)6 * TH;
    bf16* Wkb = Wrb + (size_t)HH;
    bf16* Wvb = Wkb + (size_t)HH;
    bf16* Wob = Wvb + (size_t)HH;
    bf16* pp = Wob + (size_t)HH;
    bf16* a1T = pp; pp += (size_t)H_DIM * 64;
    bf16* w1T = pp; pp += (size_t)H_DIM * 64;
    bf16* v1T = pp; pp += (size_t)H_DIM * 32;
    bf16* g1T = pp; pp += (size_t)H_DIM * 128;
    bf16* a2T = pp; pp += (size_t)H_DIM * 64;
    bf16* w2T = pp; pp += (size_t)H_DIM * 64;
    bf16* v2T = pp; pp += (size_t)H_DIM * 32;
    bf16* g2T = pp; pp += (size_t)H_DIM * 128;
    bf16* amid = pp; pp += (size_t)T_TOK * 64;
    bf16* wmid = pp; pp += (size_t)T_TOK * 64;
    bf16* vmid = pp; pp += (size_t)T_TOK * 32;
    bf16* gmid = pp; pp += (size_t)T_TOK * 128;
    bf16* ybig = pp; pp += (size_t)TH;

    // 1. cast big weights to bf16
    CastPar cp;
    cp.src[0] = W_r; cp.src[1] = W_k; cp.src[2] = W_v; cp.src[3] = W_o;
    cp.dst[0] = Wrb; cp.dst[1] = Wkb; cp.dst[2] = Wvb; cp.dst[3] = Wob;
    castw_kernel<<<dim3(HH / 4 / 256, 1, 4), 256, 0, stream>>>(cp);

    // 2. transpose + cast small weights
    TPar tp;
    tp.src[0] = a1; tp.dst[0] = a1T; tp.R[0] = H_DIM; tp.C[0] = 64;
    tp.src[1] = w1; tp.dst[1] = w1T; tp.R[1] = H_DIM; tp.C[1] = 64;
    tp.src[2] = v1; tp.dst[2] = v1T; tp.R[2] = H_DIM; tp.C[2] = 32;
    tp.src[3] = g1; tp.dst[3] = g1T; tp.R[3] = H_DIM; tp.C[3] = 128;
    tp.src[4] = a2; tp.dst[4] = a2T; tp.R[4] = 64;  tp.C[4] = H_DIM;
    tp.src[5] = w2; tp.dst[5] = w2T; tp.R[5] = 64;  tp.C[5] = H_DIM;
    tp.src[6] = v2; tp.dst[6] = v2T; tp.R[6] = 32;  tp.C[6] = H_DIM;
    tp.src[7] = g2; tp.dst[7] = g2T; tp.R[7] = 128; tp.C[7] = H_DIM;
    transpose_kernel<<<dim3((H_DIM * 128 + 255) / 256, 1, 8), 256, 0, stream>>>(tp);

    // 3. LayerNorm
    ln_kernel<<<dim3(T_TOK), 256, 0, stream>>>(x, ln1_w, ln1_b, xn, out1);

    // 4. token-shift mixes
    MixPar mp; mp.xn = xn; mp.state1 = state1;
    mp.mv[0] = x_r; mp.mv[1] = x_w; mp.mv[2] = x_k; mp.mv[3] = x_v; mp.mv[4] = x_a; mp.mv[5] = x_g;
    mp.out[0] = xrb; mp.out[1] = xwb; mp.out[2] = xkb; mp.out[3] = xvb; mp.out[4] = xab; mp.out[5] = xgb;
    mix_kernel<<<dim3(T_TOK), 256, 0, stream>>>(mp);

    // 5. r,k,v GEMMs
    BGPar bp{};
    bp.X[0] = xrb; bp.W[0] = Wrb; bp.out[0] = rb; bp.resid[0] = nullptr;
    bp.X[1] = xkb; bp.W[1] = Wkb; bp.out[1] = kb; bp.resid[1] = nullptr;
    bp.X[2] = xvb; bp.W[2] = Wvb; bp.out[2] = vb; bp.resid[2] = nullptr;
    bgemm_kernel<<<dim3(16, 8, 3), 256, 0, stream>>>(bp);

    // 6. low-rank stage 1
    GPar s1{}; s1.M = T_TOK;
    s1.X[0] = xab; s1.W[0] = a1T; s1.outB[0] = amid; s1.N[0] = 64;  s1.K[0] = H_DIM; s1.act[0] = 0;
    s1.X[1] = xwb; s1.W[1] = w1T; s1.outB[1] = wmid; s1.N[1] = 64;  s1.K[1] = H_DIM; s1.act[1] = 2;
    s1.X[2] = xvb; s1.W[2] = v1T; s1.outB[2] = vmid; s1.N[2] = 32;  s1.K[2] = H_DIM; s1.act[2] = 0;
    s1.X[3] = xgb; s1.W[3] = g1T; s1.outB[3] = gmid; s1.N[3] = 128; s1.K[3] = H_DIM; s1.act[3] = 1;
    gemm_z_kernel<<<dim3(1, 8, 4), 256, 0, stream>>>(s1);

    // 7. low-rank stage 2
    GPar s2{}; s2.M = T_TOK;
    s2.X[0] = amid; s2.W[0] = a2T; s2.outF[0] = ab;    s2.N[0] = H_DIM; s2.K[0] = 64;  s2.act[0] = 1; s2.bias[0] = a0;
    s2.X[1] = wmid; s2.W[1] = w2T; s2.outF[1] = wpre;  s2.N[1] = H_DIM; s2.K[1] = 64;  s2.act[1] = 0;
    s2.X[2] = vmid; s2.W[2] = v2T; s2.outF[2] = vresb; s2.N[2] = H_DIM; s2.K[2] = 32;  s2.act[2] = 1; s2.bias[2] = v0;
    s2.X[3] = gmid; s2.W[3] = g2T; s2.outF[3] = gb;    s2.N[3] = H_DIM; s2.K[3] = 128; s2.act[3] = 0;
    gemm_z_kernel<<<dim3(16, 8, 4), 256, 0, stream>>>(s2);

    // 8. elementwise prep
    prep_kernel<<<dim3(NH, T_TOK), 64, 0, stream>>>(kb, vb, vfirst, vresb, wpre, ab, as_s, k_k, k_a, w0);

    // 9. scan (asm pipeline + DPP reductions)
    scan_kernel<<<dim3(NH, 8), 64, 0, stream>>>(wpre, kb, vb, as_s, ab, rb, state2, yb, out2);

    // 10. groupnorm + bonus + gate
    post_kernel<<<dim3(NH, T_TOK), 64, 0, stream>>>(yb, rb, kb, vb, gb, r_k, ln_x_w, ln_x_b, ybig);

    // 11. final GEMM with residual
    BGPar bo{};
    bo.X[0] = ybig; bo.W[0] = Wob; bo.out[0] = out0; bo.resid[0] = x;
    bgemm_kernel<<<dim3(16, 8, 1), 256, 0, stream>>>(bo);

    // 12. v_first passthrough
    hipMemcpyAsync(out3, (const void*)vfirst, (size_t)TH * sizeof(float),
                   hipMemcpyDeviceToDevice, stream);
}

// Round 6
// 569.231 us; speedup vs baseline: 1.5353x; 1.2350x over previous
//
#include <hip/hip_runtime.h>
#include <hip/hip_bf16.h>
#include <cstdint>
#include <cstddef>

#define T_TOK 1024
#define H_DIM 2048
#define NH 32
#define HS 64
#define TH (T_TOK * H_DIM)
#define HH (H_DIM * H_DIM)

using short8 = __attribute__((ext_vector_type(8))) short;
using f32x4  = __attribute__((ext_vector_type(4))) float;
typedef __hip_bfloat16 bf16;

__device__ __forceinline__ float sigmoidf_(float x) { return 1.0f / (1.0f + expf(-x)); }

__device__ __forceinline__ float wsum64(float v) {
#pragma unroll
    for (int m = 32; m; m >>= 1) v += __shfl_xor(v, m, 64);
    return v;
}

// DPP sum over aligned 16-lane groups — pure VALU, no DS ops.
// xor1 (quad_perm 0xB1), xor2 (quad_perm 0x4E): all 4 lanes of a quad hold
// quad sum; half-mirror (0x141) supplies the other quad of the 8-group;
// row-mirror (0x140) supplies the other 8-group of the 16-row.
__device__ __forceinline__ float dpp_add16(float x) {
    int t;
    t = __builtin_amdgcn_update_dpp(0, __float_as_int(x), 0xB1, 0xF, 0xF, true);
    x += __int_as_float(t);
    t = __builtin_amdgcn_update_dpp(0, __float_as_int(x), 0x4E, 0xF, 0xF, true);
    x += __int_as_float(t);
    t = __builtin_amdgcn_update_dpp(0, __float_as_int(x), 0x141, 0xF, 0xF, true);
    x += __int_as_float(t);
    t = __builtin_amdgcn_update_dpp(0, __float_as_int(x), 0x140, 0xF, 0xF, true);
    x += __int_as_float(t);
    return x;
}

// ---------------- cast big weights fp32 -> bf16 ----------------
struct CastPar { const float* src[4]; bf16* dst[4]; };
__global__ __launch_bounds__(256) void castw_kernel(CastPar p) {
    int z = blockIdx.z;
    const float4* s = (const float4*)p.src[z];
    bf16* d = p.dst[z];
    int i = blockIdx.x * 256 + threadIdx.x;
    float4 v = s[i];
    int b = i * 4;
    d[b + 0] = __float2bfloat16(v.x);
    d[b + 1] = __float2bfloat16(v.y);
    d[b + 2] = __float2bfloat16(v.z);
    d[b + 3] = __float2bfloat16(v.w);
}

// ---------------- transpose + cast small weights ----------------
struct TPar { const float* src[8]; bf16* dst[8]; int R[8]; int C[8]; };
__global__ __launch_bounds__(256) void transpose_kernel(TPar p) {
    int z = blockIdx.z;
    int R = p.R[z], C = p.C[z];
    int e = blockIdx.x * 256 + threadIdx.x;
    if (e >= R * C) return;
    int r = e / C, c = e % C;
    p.dst[z][(size_t)c * R + r] = __float2bfloat16(p.src[z][e]);
}

// ---------------- LayerNorm (ln1) ----------------
__global__ __launch_bounds__(256) void ln_kernel(const float* __restrict__ x,
                                                 const float* __restrict__ w,
                                                 const float* __restrict__ b,
                                                 float* __restrict__ xn,
                                                 float* __restrict__ s1out) {
    int t = blockIdx.x, tid = threadIdx.x;
    const float* xt = x + (size_t)t * H_DIM;
    float v[8]; float s = 0.f, s2 = 0.f;
#pragma unroll
    for (int e = 0; e < 8; e++) { v[e] = xt[tid + 256 * e]; s += v[e]; s2 += v[e] * v[e]; }
    s = wsum64(s); s2 = wsum64(s2);
    __shared__ float ls[8];
    int wid = tid >> 6, ln = tid & 63;
    if (ln == 0) { ls[wid] = s; ls[4 + wid] = s2; }
    __syncthreads();
    s = ls[0] + ls[1] + ls[2] + ls[3];
    s2 = ls[4] + ls[5] + ls[6] + ls[7];
    float mu = s * (1.f / H_DIM);
    float var = s2 * (1.f / H_DIM) - mu * mu;
    float inv = rsqrtf(var + 1e-5f);
#pragma unroll
    for (int e = 0; e < 8; e++) {
        int h = tid + 256 * e;
        float o = (v[e] - mu) * inv * w[h] + b[h];
        xn[(size_t)t * H_DIM + h] = o;
        if (t == T_TOK - 1) s1out[h] = o;
    }
}

// ---------------- token-shift mixes ----------------
struct MixPar { const float* xn; const float* state1; const float* mv[6]; bf16* out[6]; };
__global__ __launch_bounds__(256) void mix_kernel(MixPar p) {
    int t = blockIdx.x, tid = threadIdx.x;
#pragma unroll
    for (int e = 0; e < 8; e++) {
        int h = tid + 256 * e;
        size_t idx = (size_t)t * H_DIM + h;
        float cur = p.xn[idx];
        float prev = (t == 0) ? p.state1[h] : p.xn[idx - H_DIM];
        float sx = prev - cur;
#pragma unroll
        for (int q = 0; q < 6; q++)
            p.out[q][idx] = __float2bfloat16(cur + p.mv[q][h] * sx);
    }
}

// ======== big GEMM: 4-stage ring global_load_lds pipeline (vmcnt(12)) ========
typedef const __attribute__((address_space(1))) uint32_t* gp1_t;
typedef __attribute__((address_space(3))) uint32_t* lp3_t;
__device__ __forceinline__ void async16(const bf16* g, short* l) {
    __builtin_amdgcn_global_load_lds((gp1_t)g, (lp3_t)l, 16, 0, 0);
}

struct BGPar { const bf16* X[4]; const bf16* W[4]; float* out[4]; const float* resid[4]; };
__global__ __launch_bounds__(256) void bgemm_kernel(BGPar p) {
    int z = blockIdx.z;
    const bf16* __restrict__ X = p.X[z];
    const bf16* __restrict__ W = p.W[z];
    float* __restrict__ out = p.out[z];
    const float* __restrict__ resid = p.resid[z];

    __shared__ short As[4][128 * 32];   // 4 stages x 8 KB
    __shared__ short Bs[4][128 * 32];   // 4 stages x 8 KB  (64 KB total)

    int m0 = blockIdx.y * 128, n0 = blockIdx.x * 128;
    int tid = threadIdx.x, lane = tid & 63, wv = tid >> 6;
    int m_off = (wv >> 1) * 64, n_off = (wv & 1) * 64;
    int lr = lane & 15, lq = lane >> 4;

    int srow = lane >> 2;
    int scol = (lane & 3) * 8;
    const bf16* Ag0 = X + (size_t)(m0 + wv * 32 + srow) * 2048 + scol;
    const bf16* Ag1 = Ag0 + (size_t)16 * 2048;
    const bf16* Bg0 = W + (size_t)(n0 + wv * 32 + srow) * 2048 + scol;
    const bf16* Bg1 = Bg0 + (size_t)16 * 2048;

    // issue stage: tile `at` (address), ring buffer `nb`
    auto issue = [&](int at, int nb) {
        int kk = at * 32;
        async16(Ag0 + kk, &As[nb][(wv * 32) * 32]);
        async16(Ag1 + kk, &As[nb][(wv * 32 + 16) * 32]);
        async16(Bg0 + kk, &Bs[nb][(wv * 32) * 32]);
        async16(Bg1 + kk, &Bs[nb][(wv * 32 + 16) * 32]);
    };

    f32x4 acc[4][4];
#pragma unroll
    for (int a = 0; a < 4; a++)
#pragma unroll
        for (int b = 0; b < 4; b++)
#pragma unroll
            for (int r = 0; r < 4; r++) acc[a][b][r] = 0.f;

    issue(0, 0); issue(1, 1); issue(2, 2);

    for (int it = 0; it < 64; it++) {
        int nt = it + 3;
        int at = nt > 63 ? 63 : nt;      // clamp address; redundant tail loads keep vmcnt uniform
        issue(at, nt & 3);               // buf (it-1)&3: consumed last iter, safe after trailing barrier
        asm volatile("s_waitcnt vmcnt(12)" ::: "memory");  // stage `it` landed; 3 stages stay in flight
        asm volatile("s_barrier" ::: "memory");            // all waves' stage-it data in LDS
        int buf = it & 3;
        short8 af[4], bfr[4];
#pragma unroll
        for (int mi = 0; mi < 4; mi++)
            af[mi] = *(const short8*)&As[buf][(m_off + mi * 16 + lr) * 32 + lq * 8];
#pragma unroll
        for (int ni = 0; ni < 4; ni++)
            bfr[ni] = *(const short8*)&Bs[buf][(n_off + ni * 16 + lr) * 32 + lq * 8];
#pragma unroll
        for (int mi = 0; mi < 4; mi++)
#pragma unroll
            for (int ni = 0; ni < 4; ni++)
                acc[mi][ni] = __builtin_amdgcn_mfma_f32_16x16x32_bf16(af[mi], bfr[ni], acc[mi][ni], 0, 0, 0);
        asm volatile("s_barrier" ::: "memory");            // buf free for overwrite next iter
    }
    asm volatile("s_waitcnt vmcnt(0)" ::: "memory");       // drain redundant tail loads

#pragma unroll
    for (int mi = 0; mi < 4; mi++)
#pragma unroll
        for (int ni = 0; ni < 4; ni++)
#pragma unroll
            for (int r = 0; r < 4; r++) {
                int rowg = m0 + m_off + mi * 16 + lq * 4 + r;
                int colg = n0 + n_off + ni * 16 + lr;
                size_t o = (size_t)rowg * 2048 + colg;
                float v = acc[mi][ni][r];
                if (resid) v += resid[o];
                out[o] = v;
            }
}

// ---------------- generic small-GEMM ----------------
#define BM 128
#define BN 128
#define BK 32
#define LDK 40

__device__ __forceinline__ void gemm_core(const bf16* __restrict__ X, const bf16* __restrict__ W,
                                          int M, int N, int K, int act,
                                          const float* __restrict__ bias,
                                          float* __restrict__ outF, bf16* __restrict__ outB) {
    __shared__ short As[BM * LDK];
    __shared__ short Bs[BN * LDK];
    int m0 = blockIdx.y * BM, n0 = blockIdx.x * BN;
    if (n0 >= N) return;
    int tid = threadIdx.x;
    int lane = tid & 63, wid = tid >> 6;
    int m_off = (wid >> 1) * 64, n_off = (wid & 1) * 64;
    int lr = lane & 15, lq = lane >> 4;

    f32x4 acc[4][4];
#pragma unroll
    for (int a = 0; a < 4; a++)
#pragma unroll
        for (int b = 0; b < 4; b++)
#pragma unroll
            for (int r = 0; r < 4; r++) acc[a][b][r] = 0.f;

    for (int k0 = 0; k0 < K; k0 += BK) {
#pragma unroll
        for (int it = 0; it < 2; it++) {
            int c = tid + it * 256;
            int r = c >> 2;
            int cc = (c & 3) * 8;
            uint4 va = *(const uint4*)(X + (size_t)(m0 + r) * K + k0 + cc);
            *(uint4*)&As[r * LDK + cc] = va;
            uint4 vb;
            if (n0 + r < N) vb = *(const uint4*)(W + (size_t)(n0 + r) * K + k0 + cc);
            else            vb = make_uint4(0u, 0u, 0u, 0u);
            *(uint4*)&Bs[r * LDK + cc] = vb;
        }
        __syncthreads();
        short8 af[4], bfr[4];
#pragma unroll
        for (int mi = 0; mi < 4; mi++)
            af[mi] = *(const short8*)&As[(m_off + mi * 16 + lr) * LDK + lq * 8];
#pragma unroll
        for (int ni = 0; ni < 4; ni++)
            bfr[ni] = *(const short8*)&Bs[(n_off + ni * 16 + lr) * LDK + lq * 8];
#pragma unroll
        for (int mi = 0; mi < 4; mi++)
#pragma unroll
            for (int ni = 0; ni < 4; ni++)
                acc[mi][ni] = __builtin_amdgcn_mfma_f32_16x16x32_bf16(af[mi], bfr[ni], acc[mi][ni], 0, 0, 0);
        __syncthreads();
    }
#pragma unroll
    for (int mi = 0; mi < 4; mi++)
#pragma unroll
        for (int ni = 0; ni < 4; ni++)
#pragma unroll
            for (int r = 0; r < 4; r++) {
                int rowg = m0 + m_off + mi * 16 + lq * 4 + r;
                int colg = n0 + n_off + ni * 16 + lr;
                if (colg < N) {
                    float v = acc[mi][ni][r];
                    if (bias) v += bias[colg];
                    if (act == 1) v = sigmoidf_(v);
                    else if (act == 2) v = tanhf(v);
                    size_t o = (size_t)rowg * N + colg;
                    if (outF) outF[o] = v;
                    else      outB[o] = __float2bfloat16(v);
                }
            }
}

struct GPar {
    const bf16* X[4]; const bf16* W[4];
    float* outF[4]; bf16* outB[4];
    const float* bias[4];
    int N[4]; int K[4]; int act[4]; int M;
};
__global__ __launch_bounds__(256) void gemm_z_kernel(GPar p) {
    int z = blockIdx.z;
    gemm_core(p.X[z], p.W[z], p.M, p.N[z], p.K[z], p.act[z], p.bias[z], p.outF[z], p.outB[z]);
}

// ---------------- elementwise prep for the scan ----------------
__global__ __launch_bounds__(64) void prep_kernel(float* __restrict__ k_io, float* __restrict__ v_io,
                                                  const float* __restrict__ v_first,
                                                  const float* __restrict__ vres,
                                                  float* __restrict__ w_io, float* __restrict__ a_io,
                                                  float* __restrict__ as_out,
                                                  const float* __restrict__ k_k,
                                                  const float* __restrict__ k_a,
                                                  const float* __restrict__ w0) {
    int h = blockIdx.x, t = blockIdx.y, i = threadIdx.x;
    int hi = h * HS + i;
    size_t idx = (size_t)t * H_DIM + hi;
    float kf = k_io[idx];
    float kk = kf * k_k[hi];
    float ss = wsum64(kk * kk);
    float kkn = kk / (sqrtf(ss) + 1e-12f);
    float a = a_io[idx];
    k_io[idx] = kf * (1.f + (a - 1.f) * k_a[hi]);
    float vv = v_io[idx];
    v_io[idx] = vv + (v_first[idx] - vv) * vres[idx];
    w_io[idx] = expf(-0.606531f * sigmoidf_(w0[hi] + w_io[idx]));
    a_io[idx] = kkn * a;     // b_seq
    as_out[idx] = -kkn;      // a_seq
}

// ---------------- WKV7 scan: 512 waves, 4 floats/lane, DPP-16 reductions ----------------
// Wave (h,q) q=0..15 owns rows q*4..q*4+3. Lane il*16+jb (il=row 0..3,
// jb=col-block 0..15) holds S[row][jb*4..+4). Reduction over 16 lanes = 4 DPP.
// 6 asm loads/step issued 4 steps ahead. vmcnt counts STORES too on gfx9 and
// retires in-order: steady-state queue = 4 stores + 24 loads; draining the
// oldest store + 6 loads = wait vmcnt(21). First iteration peeled (no stores
// yet): 18/19/20/21.
struct SlotV { f32x4 w, a, b, k, r; float v; };

#define SCAN_ISSUE(sl, tt)                                                              \
    do {                                                                                \
        int tc_ = (tt) < T_TOK ? (tt) : T_TOK - 1;                                      \
        const float* wp_ = w_s + (size_t)tc_ * H_DIM + hb;                              \
        const float* ap_ = as_s + (size_t)tc_ * H_DIM + hb;                             \
        const float* bp_ = b_s + (size_t)tc_ * H_DIM + hb;                              \
        const float* kp_ = k_s + (size_t)tc_ * H_DIM + hb;                              \
        const float* rp_ = r_s + (size_t)tc_ * H_DIM + hb;                              \
        const float* vp_ = v_s + (size_t)tc_ * H_DIM + hb;                              \
        asm volatile("global_load_dwordx4 %0, %1, %2" : "=v"((sl).w) : "v"(jow), "s"(wp_)); \
        asm volatile("global_load_dwordx4 %0, %1, %2" : "=v"((sl).a) : "v"(jow), "s"(ap_)); \
        asm volatile("global_load_dwordx4 %0, %1, %2" : "=v"((sl).b) : "v"(jow), "s"(bp_)); \
        asm volatile("global_load_dwordx4 %0, %1, %2" : "=v"((sl).k) : "v"(jow), "s"(kp_)); \
        asm volatile("global_load_dwordx4 %0, %1, %2" : "=v"((sl).r) : "v"(jow), "s"(rp_)); \
        asm volatile("global_load_dword %0, %1, %2" : "=v"((sl).v) : "v"(rowoff), "s"(vp_)); \
    } while (0)

#define SCAN_PIN(sl)                                                                    \
    asm volatile("" : "+v"((sl).w), "+v"((sl).a), "+v"((sl).b), "+v"((sl).k),           \
                      "+v"((sl).r), "+v"((sl).v))

__device__ __forceinline__ void scan_compute(float S[4], const SlotV& s,
                                             const float* __restrict__ yp, int rowoff) {
    float sa = 0.f;
#pragma unroll
    for (int e = 0; e < 4; e++) { S[e] *= s.w[e]; sa = fmaf(S[e], s.a[e], sa); }
    sa = dpp_add16(sa);
    float o = 0.f;
#pragma unroll
    for (int e = 0; e < 4; e++) {
        S[e] = fmaf(sa, s.b[e], fmaf(s.v, s.k[e], S[e]));
        o = fmaf(S[e], s.r[e], o);
    }
    o = dpp_add16(o);
    asm volatile("global_store_dword %0, %1, %2" :: "v"(rowoff), "v"(o), "s"(yp) : "memory");
}

#define SCAN_STEP(d, t, W)                                                              \
    do {                                                                                \
        asm volatile("s_waitcnt vmcnt(" W ")");                                         \
        SCAN_PIN(sv[d]);                                                                \
        scan_compute(S, sv[d], y + (size_t)(t) * H_DIM + hb, rowoff);                   \
        SCAN_ISSUE(sv[d], (t) + 4);                                                     \
    } while (0)

__global__ __launch_bounds__(64) void scan_kernel(const float* __restrict__ w_s,
                                                  const float* __restrict__ k_s,
                                                  const float* __restrict__ v_s,
                                                  const float* __restrict__ as_s,
                                                  const float* __restrict__ b_s,
                                                  const float* __restrict__ r_s,
                                                  const float* __restrict__ s2in,
                                                  float* __restrict__ y,
                                                  float* __restrict__ s2out) {
    int h = blockIdx.x, q = blockIdx.y;
    int lane = threadIdx.x;
    int il = lane >> 4, jb = lane & 15;
    int row = q * 4 + il;
    int jo = jb * 4;
    int hb = h * HS;
    int jow = jo * 4;       // byte offset of the 4-float slice
    int rowoff = row * 4;   // byte offset for v load / y store

    float S[4];
    {
        const float* s0 = s2in + (size_t)h * HS * HS + (size_t)row * HS + jo;
        float4 t0 = *(const float4*)s0;
        S[0] = t0.x; S[1] = t0.y; S[2] = t0.z; S[3] = t0.w;
    }

    SlotV sv[4];
    SCAN_ISSUE(sv[0], 0);
    SCAN_ISSUE(sv[1], 1);
    SCAN_ISSUE(sv[2], 2);
    SCAN_ISSUE(sv[3], 3);

    // peeled first iteration: no stores in the queue yet
    SCAN_STEP(0, 0, "18");
    SCAN_STEP(1, 1, "19");
    SCAN_STEP(2, 2, "20");
    SCAN_STEP(3, 3, "21");
    for (int tb = 4; tb < T_TOK; tb += 4) {
        SCAN_STEP(0, tb + 0, "21");
        SCAN_STEP(1, tb + 1, "21");
        SCAN_STEP(2, tb + 2, "21");
        SCAN_STEP(3, tb + 3, "21");
    }
    // drain outstanding asm loads before the compiler reuses their registers
    asm volatile("s_waitcnt vmcnt(0)" ::: "memory");

    {
        float* so = s2out + (size_t)h * HS * HS + (size_t)row * HS + jo;
        float4 t0;
        t0.x = S[0]; t0.y = S[1]; t0.z = S[2]; t0.w = S[3];
        *(float4*)so = t0;
    }
}

// ---------------- groupnorm + bonus + gate -> bf16 ----------------
__global__ __launch_bounds__(64) void post_kernel(const float* __restrict__ y,
                                                  const float* __restrict__ r_s,
                                                  const float* __restrict__ k_s,
                                                  const float* __restrict__ v_s,
                                                  const float* __restrict__ g_s,
                                                  const float* __restrict__ r_k,
                                                  const float* __restrict__ lnw,
                                                  const float* __restrict__ lnb,
                                                  bf16* __restrict__ ybig) {
    int h = blockIdx.x, t = blockIdx.y, i = threadIdx.x;
    int hi = h * HS + i;
    size_t idx = (size_t)t * H_DIM + hi;
    float yv = y[idx];
    float mu = wsum64(yv) * (1.f / HS);
    float d = yv - mu;
    float var = wsum64(d * d) * (1.f / HS);
    float yn = d * rsqrtf(var + 0.00064f);
    float bd = wsum64(r_s[idx] * k_s[idx] * r_k[hi]);
    float val = (yn * lnw[hi] + lnb[hi] + bd * v_s[idx]) * g_s[idx];
    ybig[idx] = __float2bfloat16(val);
}

// ---------------- launcher ----------------
extern "C" void kernel_launch(void* const* d_in, const int* in_sizes, int n_in,
                              void* d_out, int out_size, void* d_ws, size_t ws_size,
                              hipStream_t stream) {
    const float* x      = (const float*)d_in[0];
    const float* state1 = (const float*)d_in[1];
    const float* state2 = (const float*)d_in[2];
    const float* vfirst = (const float*)d_in[3];
    const float* x_r = (const float*)d_in[4];
    const float* x_w = (const float*)d_in[5];
    const float* x_k = (const float*)d_in[6];
    const float* x_v = (const float*)d_in[7];
    const float* x_a = (const float*)d_in[8];
    const float* x_g = (const float*)d_in[9];
    const float* W_r = (const float*)d_in[10];
    const float* W_k = (const float*)d_in[11];
    const float* W_v = (const float*)d_in[12];
    const float* W_o = (const float*)d_in[13];
    const float* w0 = (const float*)d_in[14];
    const float* w1 = (const float*)d_in[15];
    const float* w2 = (const float*)d_in[16];
    const float* a0 = (const float*)d_in[17];
    const float* a1 = (const float*)d_in[18];
    const float* a2 = (const float*)d_in[19];
    const float* v0 = (const float*)d_in[20];
    const float* v1 = (const float*)d_in[21];
    const float* v2 = (const float*)d_in[22];
    const float* g1 = (const float*)d_in[23];
    const float* g2 = (const float*)d_in[24];
    const float* k_k = (const float*)d_in[25];
    const float* k_a = (const float*)d_in[26];
    const float* r_k = (const float*)d_in[27];
    const float* ln_x_w = (const float*)d_in[28];
    const float* ln_x_b = (const float*)d_in[29];
    const float* ln1_w = (const float*)d_in[30];
    const float* ln1_b = (const float*)d_in[31];

    float* out0 = (float*)d_out;
    float* out1 = out0 + TH;
    float* out2 = out1 + H_DIM;
    float* out3 = out2 + NH * HS * HS;

    float* F = (float*)d_ws;
    float* xn   = F;                          // dead after mix; reused as as_s
    float* as_s = F;
    float* rb   = F + (size_t)1 * TH;
    float* kb   = F + (size_t)2 * TH;
    float* vb   = F + (size_t)3 * TH;
    float* ab   = F + (size_t)4 * TH;
    float* wpre = F + (size_t)5 * TH;
    float* vresb= F + (size_t)6 * TH;
    float* gb   = F + (size_t)7 * TH;
    float* yb   = F + (size_t)8 * TH;
    bf16* B = (bf16*)(F + (size_t)9 * TH);
    bf16 *xrb = B, *xwb = B + (size_t)TH, *xkb = B + (size_t)2 * TH,
         *xvb = B + (size_t)3 * TH, *xab = B + (size_t)4 * TH, *xgb = B + (size_t)5 * TH;
    bf16* Wrb = B + (size_t)6 * TH;
    bf16* Wkb = Wrb + (size_t)HH;
    bf16* Wvb = Wkb + (size_t)HH;
    bf16* Wob = Wvb + (size_t)HH;
    bf16* pp = Wob + (size_t)HH;
    bf16* a1T = pp; pp += (size_t)H_DIM * 64;
    bf16* w1T = pp; pp += (size_t)H_DIM * 64;
    bf16* v1T = pp; pp += (size_t)H_DIM * 32;
    bf16* g1T = pp; pp += (size_t)H_DIM * 128;
    bf16* a2T = pp; pp += (size_t)H_DIM * 64;
    bf16* w2T = pp; pp += (size_t)H_DIM * 64;
    bf16* v2T = pp; pp += (size_t)H_DIM * 32;
    bf16* g2T = pp; pp += (size_t)H_DIM * 128;
    bf16* amid = pp; pp += (size_t)T_TOK * 64;
    bf16* wmid = pp; pp += (size_t)T_TOK * 64;
    bf16* vmid = pp; pp += (size_t)T_TOK * 32;
    bf16* gmid = pp; pp += (size_t)T_TOK * 128;
    bf16* ybig = pp; pp += (size_t)TH;

    // 1. cast big weights to bf16
    CastPar cp;
    cp.src[0] = W_r; cp.src[1] = W_k; cp.src[2] = W_v; cp.src[3] = W_o;
    cp.dst[0] = Wrb; cp.dst[1] = Wkb; cp.dst[2] = Wvb; cp.dst[3] = Wob;
    castw_kernel<<<dim3(HH / 4 / 256, 1, 4), 256, 0, stream>>>(cp);

    // 2. transpose + cast small weights
    TPar tp;
    tp.src[0] = a1; tp.dst[0] = a1T; tp.R[0] = H_DIM; tp.C[0] = 64;
    tp.src[1] = w1; tp.dst[1] = w1T; tp.R[1] = H_DIM; tp.C[1] = 64;
    tp.src[2] = v1; tp.dst[2] = v1T; tp.R[2] = H_DIM; tp.C[2] = 32;
    tp.src[3] = g1; tp.dst[3] = g1T; tp.R[3] = H_DIM; tp.C[3] = 128;
    tp.src[4] = a2; tp.dst[4] = a2T; tp.R[4] = 64;  tp.C[4] = H_DIM;
    tp.src[5] = w2; tp.dst[5] = w2T; tp.R[5] = 64;  tp.C[5] = H_DIM;
    tp.src[6] = v2; tp.dst[6] = v2T; tp.R[6] = 32;  tp.C[6] = H_DIM;
    tp.src[7] = g2; tp.dst[7] = g2T; tp.R[7] = 128; tp.C[7] = H_DIM;
    transpose_kernel<<<dim3((H_DIM * 128 + 255) / 256, 1, 8), 256, 0, stream>>>(tp);

    // 3. LayerNorm
    ln_kernel<<<dim3(T_TOK), 256, 0, stream>>>(x, ln1_w, ln1_b, xn, out1);

    // 4. token-shift mixes
    MixPar mp; mp.xn = xn; mp.state1 = state1;
    mp.mv[0] = x_r; mp.mv[1] = x_w; mp.mv[2] = x_k; mp.mv[3] = x_v; mp.mv[4] = x_a; mp.mv[5] = x_g;
    mp.out[0] = xrb; mp.out[1] = xwb; mp.out[2] = xkb; mp.out[3] = xvb; mp.out[4] = xab; mp.out[5] = xgb;
    mix_kernel<<<dim3(T_TOK), 256, 0, stream>>>(mp);

    // 5. r,k,v GEMMs (4-stage pipelined)
    BGPar bp{};
    bp.X[0] = xrb; bp.W[0] = Wrb; bp.out[0] = rb; bp.resid[0] = nullptr;
    bp.X[1] = xkb; bp.W[1] = Wkb; bp.out[1] = kb; bp.resid[1] = nullptr;
    bp.X[2] = xvb; bp.W[2] = Wvb; bp.out[2] = vb; bp.resid[2] = nullptr;
    bgemm_kernel<<<dim3(16, 8, 3), 256, 0, stream>>>(bp);

    // 6. low-rank stage 1
    GPar s1{}; s1.M = T_TOK;
    s1.X[0] = xab; s1.W[0] = a1T; s1.outB[0] = amid; s1.N[0] = 64;  s1.K[0] = H_DIM; s1.act[0] = 0;
    s1.X[1] = xwb; s1.W[1] = w1T; s1.outB[1] = wmid; s1.N[1] = 64;  s1.K[1] = H_DIM; s1.act[1] = 2;
    s1.X[2] = xvb; s1.W[2] = v1T; s1.outB[2] = vmid; s1.N[2] = 32;  s1.K[2] = H_DIM; s1.act[2] = 0;
    s1.X[3] = xgb; s1.W[3] = g1T; s1.outB[3] = gmid; s1.N[3] = 128; s1.K[3] = H_DIM; s1.act[3] = 1;
    gemm_z_kernel<<<dim3(1, 8, 4), 256, 0, stream>>>(s1);

    // 7. low-rank stage 2
    GPar s2{}; s2.M = T_TOK;
    s2.X[0] = amid; s2.W[0] = a2T; s2.outF[0] = ab;    s2.N[0] = H_DIM; s2.K[0] = 64;  s2.act[0] = 1; s2.bias[0] = a0;
    s2.X[1] = wmid; s2.W[1] = w2T; s2.outF[1] = wpre;  s2.N[1] = H_DIM; s2.K[1] = 64;  s2.act[1] = 0;
    s2.X[2] = vmid; s2.W[2] = v2T; s2.outF[2] = vresb; s2.N[2] = H_DIM; s2.K[2] = 32;  s2.act[2] = 1; s2.bias[2] = v0;
    s2.X[3] = gmid; s2.W[3] = g2T; s2.outF[3] = gb;    s2.N[3] = H_DIM; s2.K[3] = 128; s2.act[3] = 0;
    gemm_z_kernel<<<dim3(16, 8, 4), 256, 0, stream>>>(s2);

    // 8. elementwise prep
    prep_kernel<<<dim3(NH, T_TOK), 64, 0, stream>>>(kb, vb, vfirst, vresb, wpre, ab, as_s, k_k, k_a, w0);

    // 9. scan (512 waves, 4 floats/lane, DPP-16)
    scan_kernel<<<dim3(NH, 16), 64, 0, stream>>>(wpre, kb, vb, as_s, ab, rb, state2, yb, out2);

    // 10. groupnorm + bonus + gate
    post_kernel<<<dim3(NH, T_TOK), 64, 0, stream>>>(yb, rb, kb, vb, gb, r_k, ln_x_w, ln_x_b, ybig);

    // 11. final GEMM with residual
    BGPar bo{};
    bo.X[0] = ybig; bo.W[0] = Wob; bo.out[0] = out0; bo.resid[0] = x;
    bgemm_kernel<<<dim3(16, 8, 1), 256, 0, stream>>>(bo);

    // 12. v_first passthrough
    hipMemcpyAsync(out3, (const void*)vfirst, (size_t)TH * sizeof(float),
                   hipMemcpyDeviceToDevice, stream);
}